// Round 1
// baseline (4137.937 us; speedup 1.0000x reference)
//
#include <hip/hip_runtime.h>
#include <cstddef>

#define SLOPE 0.01f
#define BN_EPS 1e-5f

// ---------------------------------------------------------------------------
// Conv1d (+bias) with optional second input source read through x2 nearest
// upsample (idx = i>>1). Also accumulates per-channel sum / sumsq for BN
// training-mode batch stats via block reduction + atomics.
// Grid: (ceil(L_out/256), Cout, B), block 256 along output positions.
// ---------------------------------------------------------------------------
__global__ __launch_bounds__(256) void conv_stats_kernel(
    const float* __restrict__ xA, int CA,
    const float* __restrict__ xB, int CB,           // xB length = L_in>>1 (may be null if CB==0)
    const float* __restrict__ w, const float* __restrict__ bias,
    float* __restrict__ y,
    int L_in, int L_out, int K, int stride, int pad,
    float* __restrict__ ch_sum, float* __restrict__ ch_sumsq)
{
    const int o    = blockIdx.x * blockDim.x + threadIdx.x;
    const int co   = blockIdx.y;
    const int b    = blockIdx.z;
    const int Cout = gridDim.y;
    const int Cin  = CA + CB;

    float acc = 0.0f;
    if (o < L_out) {
        const float* wrow = w + (size_t)co * Cin * K;
        const int base = o * stride - pad;
        for (int c = 0; c < CA; ++c) {
            const float* xp = xA + ((size_t)b * CA + c) * L_in;
            #pragma unroll 3
            for (int t = 0; t < K; ++t) {
                int i = base + t;
                float xv = (i >= 0 && i < L_in) ? xp[i] : 0.0f;
                acc = fmaf(wrow[c * K + t], xv, acc);
            }
        }
        if (CB > 0) {
            const int LB = L_in >> 1;
            for (int c = 0; c < CB; ++c) {
                const float* xp = xB + ((size_t)b * CB + c) * LB;
                const float* wr = wrow + (size_t)(CA + c) * K;
                #pragma unroll 3
                for (int t = 0; t < K; ++t) {
                    int i = base + t;
                    float xv = (i >= 0 && i < L_in) ? xp[i >> 1] : 0.0f;
                    acc = fmaf(wr[t], xv, acc);
                }
            }
        }
        acc += bias[co];
        y[((size_t)b * Cout + co) * L_out + o] = acc;
    }

    // --- block reduction of (acc, acc^2), one atomicAdd pair per block ---
    float v  = (o < L_out) ? acc : 0.0f;
    float v2 = v * v;
    #pragma unroll
    for (int off = 32; off > 0; off >>= 1) {
        v  += __shfl_down(v,  off, 64);
        v2 += __shfl_down(v2, off, 64);
    }
    __shared__ float s1[4], s2[4];
    const int lane = threadIdx.x & 63;
    const int wid  = threadIdx.x >> 6;
    if (lane == 0) { s1[wid] = v; s2[wid] = v2; }
    __syncthreads();
    if (threadIdx.x == 0) {
        float t1 = s1[0] + s1[1] + s1[2] + s1[3];
        float t2 = s2[0] + s2[1] + s2[2] + s2[3];
        atomicAdd(&ch_sum[co],   t1);
        atomicAdd(&ch_sumsq[co], t2);
    }
}

// sum/sumsq -> per-channel affine (scale = g*rstd, shift = be - g*rstd*mean)
__global__ void bn_prep_kernel(const float* __restrict__ ch_sum,
                               const float* __restrict__ ch_sumsq,
                               const float* __restrict__ g,
                               const float* __restrict__ be,
                               float* __restrict__ scale,
                               float* __restrict__ shift,
                               int C, float invN)
{
    int c = blockIdx.x * blockDim.x + threadIdx.x;
    if (c < C) {
        float m  = ch_sum[c] * invN;
        float v  = ch_sumsq[c] * invN - m * m;   // biased variance
        float r  = rsqrtf(v + BN_EPS);
        float sc = g[c] * r;
        scale[c] = sc;
        shift[c] = be[c] - sc * m;
    }
}

// In-place y = lrelu(scale[c]*y + shift[c]).  Grid: (L/256, C, B)
__global__ __launch_bounds__(256) void bn_lrelu_kernel(
    float* __restrict__ y,
    const float* __restrict__ scale, const float* __restrict__ shift,
    int L)
{
    const int o = blockIdx.x * blockDim.x + threadIdx.x;
    const int c = blockIdx.y;
    const int b = blockIdx.z;
    const int C = gridDim.y;
    if (o < L) {
        size_t idx = ((size_t)b * C + c) * L + o;
        float v = fmaf(y[idx], scale[c], shift[c]);
        y[idx] = (v >= 0.0f) ? v : SLOPE * v;
    }
}

// Banded correlation fusion.  f2: (B, C, N) -> feat: (B, 11, N)
// feat[b,d+5,i] = sum_c sum_{j=-1..1} f2[b,c,cl(i+j)] * f2[b,c,cl(cl(i+d)+j)]
__global__ __launch_bounds__(256) void fusion_kernel(
    const float* __restrict__ f2, float* __restrict__ feat,
    int C, int N)
{
    const int i = blockIdx.x * blockDim.x + threadIdx.x;
    const int d = (int)blockIdx.y - 5;
    const int b = blockIdx.z;
    if (i >= N) return;
    const int i2 = min(max(i + d, 0), N - 1);
    const int a0 = max(i - 1, 0), a1 = i, a2 = min(i + 1, N - 1);
    const int b0 = max(i2 - 1, 0), b1 = i2, b2 = min(i2 + 1, N - 1);
    const float* fb = f2 + (size_t)b * C * N;
    float acc = 0.0f;
    for (int c = 0; c < C; ++c) {
        const float* fc = fb + (size_t)c * N;
        acc = fmaf(fc[a0], fc[b0], acc);
        acc = fmaf(fc[a1], fc[b1], acc);
        acc = fmaf(fc[a2], fc[b2], acc);
    }
    feat[((size_t)b * 11 + (d + 5)) * N + i] = acc;
}

// Flow head epilogue: normalize + lrelu + transpose (B,2,N) -> (B,N,2)
__global__ __launch_bounds__(256) void bn_lrelu_transpose_kernel(
    const float* __restrict__ y,
    const float* __restrict__ scale, const float* __restrict__ shift,
    float* __restrict__ out, int N)
{
    const int i = blockIdx.x * blockDim.x + threadIdx.x;
    const int b = blockIdx.z;
    if (i >= N) return;
    #pragma unroll
    for (int c = 0; c < 2; ++c) {
        float v = fmaf(y[((size_t)b * 2 + c) * N + i], scale[c], shift[c]);
        v = (v >= 0.0f) ? v : SLOPE * v;
        out[((size_t)b * N + i) * 2 + c] = v;
    }
}

// ---------------------------------------------------------------------------

static void run_layer(const float* xA, int CA, const float* xB, int CB,
                      const float* w, const float* b, const float* g, const float* be,
                      float* y, int Batch, int L_in, int L_out, int Cout,
                      int K, int stride, int pad,
                      float* stats, hipStream_t stream)
{
    float* ch_sum   = stats;
    float* ch_sumsq = stats + 256;
    float* scale    = stats + 512;
    float* shift    = stats + 768;
    hipMemsetAsync(stats, 0, 512 * sizeof(float), stream);

    dim3 grid((L_out + 255) / 256, Cout, Batch);
    conv_stats_kernel<<<grid, 256, 0, stream>>>(xA, CA, xB, CB, w, b, y,
                                                L_in, L_out, K, stride, pad,
                                                ch_sum, ch_sumsq);
    float invN = 1.0f / (float)((size_t)Batch * L_out);
    bn_prep_kernel<<<1, 256, 0, stream>>>(ch_sum, ch_sumsq, g, be, scale, shift, Cout, invN);
    bn_lrelu_kernel<<<grid, 256, 0, stream>>>(y, scale, shift, L_out);
}

extern "C" void kernel_launch(void* const* d_in, const int* in_sizes, int n_in,
                              void* d_out, int out_size, void* d_ws, size_t ws_size,
                              hipStream_t stream)
{
    const int B = 8, N = 16384;
    const float* scan1 = (const float*)d_in[0];   // (B, N, 1) == (B, 1, N) since CIN=1

    const float* enc0_w = (const float*)d_in[1];
    const float* enc0_b = (const float*)d_in[2];
    const float* enc0_g = (const float*)d_in[3];
    const float* enc0_be= (const float*)d_in[4];
    const float* enc1_w = (const float*)d_in[5];
    const float* enc1_b = (const float*)d_in[6];
    const float* enc1_g = (const float*)d_in[7];
    const float* enc1_be= (const float*)d_in[8];
    const float* enc2_w = (const float*)d_in[9];
    const float* enc2_b = (const float*)d_in[10];
    const float* enc2_g = (const float*)d_in[11];
    const float* enc2_be= (const float*)d_in[12];
    const float* dec1_w = (const float*)d_in[13];
    const float* dec1_b = (const float*)d_in[14];
    const float* dec1_g = (const float*)d_in[15];
    const float* dec1_be= (const float*)d_in[16];
    const float* dec0_w = (const float*)d_in[17];
    const float* dec0_b = (const float*)d_in[18];
    const float* dec0_g = (const float*)d_in[19];
    const float* dec0_be= (const float*)d_in[20];
    const float* flow_w = (const float*)d_in[21];
    const float* flow_b = (const float*)d_in[22];
    const float* flow_g = (const float*)d_in[23];
    const float* flow_be= (const float*)d_in[24];

    float* ws = (float*)d_ws;
    // workspace layout (floats)
    const size_t off_f0   = 0;                       // (B,  64, 8192) = 4194304
    const size_t off_f1   = off_f0  + 4194304;       // (B, 128, 4096) = 4194304
    const size_t off_f2   = off_f1  + 4194304;       // (B, 256, 2048) = 4194304 ; reused for dec1 out
    const size_t off_feat = off_f2  + 4194304;       // (B,  11, 2048) = 180224
    const size_t off_d0   = off_feat + 180224;       // (B, 128, 8192) = 8388608
    const size_t off_fl   = off_d0  + 8388608;       // (B,   2,16384) = 262144
    const size_t off_st   = off_fl  + 262144;        // stats scratch  = 1024

    float* f0   = ws + off_f0;
    float* f1   = ws + off_f1;
    float* f2   = ws + off_f2;
    float* feat = ws + off_feat;
    float* d1   = ws + off_f2;    // reuse f2's buffer after fusion
    float* d0   = ws + off_d0;
    float* fl   = ws + off_fl;
    float* st   = ws + off_st;

    // ---- encoders (stride 2) ----
    run_layer(scan1, 1,   nullptr, 0,   enc0_w, enc0_b, enc0_g, enc0_be,
              f0, B, 16384, 8192,  64, 3, 2, 1, st, stream);
    run_layer(f0,   64,   nullptr, 0,   enc1_w, enc1_b, enc1_g, enc1_be,
              f1, B,  8192, 4096, 128, 3, 2, 1, st, stream);
    run_layer(f1,  128,   nullptr, 0,   enc2_w, enc2_b, enc2_g, enc2_be,
              f2, B,  4096, 2048, 256, 3, 2, 1, st, stream);

    // ---- fusion (banded correlation, D=5, K=3) ----
    {
        dim3 grid((2048 + 255) / 256, 11, B);
        fusion_kernel<<<grid, 256, 0, stream>>>(f2, feat, 256, 2048);
    }

    // ---- decoders: concat(A, upsample_x2(B)) handled inside the conv ----
    run_layer(f1, 128,  feat, 11,  dec1_w, dec1_b, dec1_g, dec1_be,
              d1, B, 4096, 4096, 128, 3, 1, 1, st, stream);
    run_layer(f0,  64,  d1, 128,   dec0_w, dec0_b, dec0_g, dec0_be,
              d0, B, 8192, 8192, 128, 3, 1, 1, st, stream);

    // ---- flow head (k=1) with fused transpose epilogue ----
    {
        float* ch_sum = st, *ch_sumsq = st + 256, *scale = st + 512, *shift = st + 768;
        hipMemsetAsync(st, 0, 512 * sizeof(float), stream);
        dim3 grid((16384 + 255) / 256, 2, B);
        conv_stats_kernel<<<grid, 256, 0, stream>>>(scan1, 1, d0, 128, flow_w, flow_b,
                                                    fl, 16384, 16384, 1, 1, 0,
                                                    ch_sum, ch_sumsq);
        float invN = 1.0f / (float)((size_t)B * 16384);
        bn_prep_kernel<<<1, 256, 0, stream>>>(ch_sum, ch_sumsq, flow_g, flow_be,
                                              scale, shift, 2, invN);
        dim3 tgrid((16384 + 255) / 256, 1, B);
        bn_lrelu_transpose_kernel<<<tgrid, 256, 0, stream>>>(fl, scale, shift,
                                                             (float*)d_out, 16384);
    }
}

// Round 2
// 881.915 us; speedup vs baseline: 4.6920x; 4.6920x over previous
//
#include <hip/hip_runtime.h>
#include <cstddef>

#define SLOPE 0.01f
#define BN_EPS 1e-5f

// ---------------------------------------------------------------------------
// Register-tiled Conv1d (+bias) with optional second source read through x2
// nearest upsample (idx = i>>1). Each thread computes COT output channels at
// one output position: x values loaded once, reused COT times; weight loads
// are wave-uniform (co base uniform) -> scalar s_load, off the VMEM pipe.
// Also accumulates per-channel sum / sumsq for BN training-mode batch stats.
// Grid: (L_out/256, Cout/COT, B), block 256 along output positions.
// ---------------------------------------------------------------------------
template<int COT, int K>
__global__ __launch_bounds__(256) void conv_tiled_kernel(
    const float* __restrict__ xA, int CA,
    const float* __restrict__ xB, int CB,      // xB length = L_in>>1 (null if CB==0)
    const float* __restrict__ w, const float* __restrict__ bias,
    float* __restrict__ y,
    int L_in, int L_out, int stride, int pad, int Cout,
    float* __restrict__ ch_sum, float* __restrict__ ch_sumsq)
{
    const int o  = blockIdx.x * 256 + threadIdx.x;
    const int cb = blockIdx.y * COT;          // wave-uniform channel base
    const int b  = blockIdx.z;
    const int Cin = CA + CB;
    const bool valid = (o < L_out);

    float acc[COT];
    #pragma unroll
    for (int j = 0; j < COT; ++j) acc[j] = 0.0f;

    const int base = o * stride - pad;
    const float* wbase = w + (size_t)cb * Cin * K;   // uniform

    #pragma unroll 4
    for (int c = 0; c < CA; ++c) {
        const float* xp = xA + ((size_t)b * CA + c) * L_in;
        float xv[K];
        #pragma unroll
        for (int t = 0; t < K; ++t) {
            int i = base + t;
            xv[t] = (i >= 0 && i < L_in) ? xp[i] : 0.0f;
        }
        #pragma unroll
        for (int j = 0; j < COT; ++j) {
            const float* wr = wbase + (size_t)j * Cin * K + c * K;
            #pragma unroll
            for (int t = 0; t < K; ++t)
                acc[j] = fmaf(wr[t], xv[t], acc[j]);
        }
    }
    if (CB > 0) {
        const int LB = L_in >> 1;
        #pragma unroll 4
        for (int c = 0; c < CB; ++c) {
            const float* xp = xB + ((size_t)b * CB + c) * LB;
            float xv[K];
            #pragma unroll
            for (int t = 0; t < K; ++t) {
                int i = base + t;
                xv[t] = (i >= 0 && i < L_in) ? xp[i >> 1] : 0.0f;
            }
            #pragma unroll
            for (int j = 0; j < COT; ++j) {
                const float* wr = wbase + (size_t)j * Cin * K + (CA + c) * K;
                #pragma unroll
                for (int t = 0; t < K; ++t)
                    acc[j] = fmaf(wr[t], xv[t], acc[j]);
            }
        }
    }

    #pragma unroll
    for (int j = 0; j < COT; ++j) acc[j] += bias[cb + j];

    if (valid) {
        #pragma unroll
        for (int j = 0; j < COT; ++j)
            y[((size_t)b * Cout + cb + j) * L_out + o] = acc[j];
    }

    // --- block reduction of (sum, sumsq) per channel, COT atomics/block ---
    __shared__ float s1[4 * COT], s2[4 * COT];
    const int lane = threadIdx.x & 63;
    const int wid  = threadIdx.x >> 6;
    #pragma unroll
    for (int j = 0; j < COT; ++j) {
        float v  = valid ? acc[j] : 0.0f;
        float v2 = v * v;
        #pragma unroll
        for (int off = 32; off > 0; off >>= 1) {
            v  += __shfl_down(v,  off, 64);
            v2 += __shfl_down(v2, off, 64);
        }
        if (lane == 0) { s1[wid * COT + j] = v; s2[wid * COT + j] = v2; }
    }
    __syncthreads();
    if (threadIdx.x < COT) {
        int j = threadIdx.x;
        float t1 = s1[j] + s1[COT + j] + s1[2 * COT + j] + s1[3 * COT + j];
        float t2 = s2[j] + s2[COT + j] + s2[2 * COT + j] + s2[3 * COT + j];
        atomicAdd(&ch_sum[cb + j],   t1);
        atomicAdd(&ch_sumsq[cb + j], t2);
    }
}

// sum/sumsq -> per-channel affine (scale = g*rstd, shift = be - g*rstd*mean)
__global__ void bn_prep_kernel(const float* __restrict__ ch_sum,
                               const float* __restrict__ ch_sumsq,
                               const float* __restrict__ g,
                               const float* __restrict__ be,
                               float* __restrict__ scale,
                               float* __restrict__ shift,
                               int C, float invN)
{
    int c = blockIdx.x * blockDim.x + threadIdx.x;
    if (c < C) {
        float m  = ch_sum[c] * invN;
        float v  = ch_sumsq[c] * invN - m * m;   // biased variance
        float r  = rsqrtf(v + BN_EPS);
        float sc = g[c] * r;
        scale[c] = sc;
        shift[c] = be[c] - sc * m;
    }
}

// In-place y = lrelu(scale[c]*y + shift[c]), float4. Grid: (L/1024, C, B)
__global__ __launch_bounds__(256) void bn_lrelu4_kernel(
    float* __restrict__ y,
    const float* __restrict__ scale, const float* __restrict__ shift,
    int L4)   // L/4
{
    const int o = blockIdx.x * blockDim.x + threadIdx.x;
    const int c = blockIdx.y;
    const int b = blockIdx.z;
    const int C = gridDim.y;
    if (o < L4) {
        float4* yp = (float4*)(y + ((size_t)b * C + c) * (size_t)L4 * 4);
        float sc = scale[c], sh = shift[c];
        float4 v = yp[o];
        v.x = fmaf(v.x, sc, sh); v.x = (v.x >= 0.0f) ? v.x : SLOPE * v.x;
        v.y = fmaf(v.y, sc, sh); v.y = (v.y >= 0.0f) ? v.y : SLOPE * v.y;
        v.z = fmaf(v.z, sc, sh); v.z = (v.z >= 0.0f) ? v.z : SLOPE * v.z;
        v.w = fmaf(v.w, sc, sh); v.w = (v.w >= 0.0f) ? v.w : SLOPE * v.w;
        yp[o] = v;
    }
}

// Banded correlation fusion.  f2: (B, C, N) -> feat: (B, 11, N)
__global__ __launch_bounds__(256) void fusion_kernel(
    const float* __restrict__ f2, float* __restrict__ feat,
    int C, int N)
{
    const int i = blockIdx.x * blockDim.x + threadIdx.x;
    const int d = (int)blockIdx.y - 5;
    const int b = blockIdx.z;
    if (i >= N) return;
    const int i2 = min(max(i + d, 0), N - 1);
    const int a0 = max(i - 1, 0), a1 = i, a2 = min(i + 1, N - 1);
    const int b0 = max(i2 - 1, 0), b1 = i2, b2 = min(i2 + 1, N - 1);
    const float* fb = f2 + (size_t)b * C * N;
    float acc = 0.0f;
    for (int c = 0; c < C; ++c) {
        const float* fc = fb + (size_t)c * N;
        acc = fmaf(fc[a0], fc[b0], acc);
        acc = fmaf(fc[a1], fc[b1], acc);
        acc = fmaf(fc[a2], fc[b2], acc);
    }
    feat[((size_t)b * 11 + (d + 5)) * N + i] = acc;
}

// Flow head epilogue: normalize + lrelu + transpose (B,2,N) -> (B,N,2)
__global__ __launch_bounds__(256) void bn_lrelu_transpose_kernel(
    const float* __restrict__ y,
    const float* __restrict__ scale, const float* __restrict__ shift,
    float* __restrict__ out, int N)
{
    const int i = blockIdx.x * blockDim.x + threadIdx.x;
    const int b = blockIdx.z;
    if (i >= N) return;
    #pragma unroll
    for (int c = 0; c < 2; ++c) {
        float v = fmaf(y[((size_t)b * 2 + c) * N + i], scale[c], shift[c]);
        v = (v >= 0.0f) ? v : SLOPE * v;
        out[((size_t)b * N + i) * 2 + c] = v;
    }
}

// ---------------------------------------------------------------------------

static void run_layer83(const float* xA, int CA, const float* xB, int CB,
                        const float* w, const float* b, const float* g, const float* be,
                        float* y, int Batch, int L_in, int L_out, int Cout,
                        int stride, float* stats, hipStream_t stream)
{
    float* ch_sum   = stats;
    float* ch_sumsq = stats + 256;
    float* scale    = stats + 512;
    float* shift    = stats + 768;
    hipMemsetAsync(stats, 0, 512 * sizeof(float), stream);

    dim3 cgrid(L_out / 256, Cout / 8, Batch);
    conv_tiled_kernel<8, 3><<<cgrid, 256, 0, stream>>>(
        xA, CA, xB, CB, w, b, y, L_in, L_out, stride, 1, Cout, ch_sum, ch_sumsq);
    float invN = 1.0f / (float)((size_t)Batch * L_out);
    bn_prep_kernel<<<1, 256, 0, stream>>>(ch_sum, ch_sumsq, g, be, scale, shift, Cout, invN);
    dim3 ngrid((L_out / 4 + 255) / 256, Cout, Batch);
    bn_lrelu4_kernel<<<ngrid, 256, 0, stream>>>(y, scale, shift, L_out / 4);
}

extern "C" void kernel_launch(void* const* d_in, const int* in_sizes, int n_in,
                              void* d_out, int out_size, void* d_ws, size_t ws_size,
                              hipStream_t stream)
{
    const int B = 8, N = 16384;
    const float* scan1 = (const float*)d_in[0];   // (B, N, 1) == (B, 1, N)

    const float* enc0_w = (const float*)d_in[1];
    const float* enc0_b = (const float*)d_in[2];
    const float* enc0_g = (const float*)d_in[3];
    const float* enc0_be= (const float*)d_in[4];
    const float* enc1_w = (const float*)d_in[5];
    const float* enc1_b = (const float*)d_in[6];
    const float* enc1_g = (const float*)d_in[7];
    const float* enc1_be= (const float*)d_in[8];
    const float* enc2_w = (const float*)d_in[9];
    const float* enc2_b = (const float*)d_in[10];
    const float* enc2_g = (const float*)d_in[11];
    const float* enc2_be= (const float*)d_in[12];
    const float* dec1_w = (const float*)d_in[13];
    const float* dec1_b = (const float*)d_in[14];
    const float* dec1_g = (const float*)d_in[15];
    const float* dec1_be= (const float*)d_in[16];
    const float* dec0_w = (const float*)d_in[17];
    const float* dec0_b = (const float*)d_in[18];
    const float* dec0_g = (const float*)d_in[19];
    const float* dec0_be= (const float*)d_in[20];
    const float* flow_w = (const float*)d_in[21];
    const float* flow_b = (const float*)d_in[22];
    const float* flow_g = (const float*)d_in[23];
    const float* flow_be= (const float*)d_in[24];

    float* ws = (float*)d_ws;
    const size_t off_f0   = 0;                       // (B,  64, 8192)
    const size_t off_f1   = off_f0  + 4194304;       // (B, 128, 4096)
    const size_t off_f2   = off_f1  + 4194304;       // (B, 256, 2048) ; reused for dec1 out
    const size_t off_feat = off_f2  + 4194304;       // (B,  11, 2048)
    const size_t off_d0   = off_feat + 180224;       // (B, 128, 8192)
    const size_t off_fl   = off_d0  + 8388608;       // (B,   2,16384)
    const size_t off_st   = off_fl  + 262144;        // stats scratch

    float* f0   = ws + off_f0;
    float* f1   = ws + off_f1;
    float* f2   = ws + off_f2;
    float* feat = ws + off_feat;
    float* d1   = ws + off_f2;    // reuse f2's buffer after fusion
    float* d0   = ws + off_d0;
    float* fl   = ws + off_fl;
    float* st   = ws + off_st;

    // ---- encoders (stride 2) ----
    run_layer83(scan1, 1,   nullptr, 0,   enc0_w, enc0_b, enc0_g, enc0_be,
                f0, B, 16384, 8192,  64, 2, st, stream);
    run_layer83(f0,   64,   nullptr, 0,   enc1_w, enc1_b, enc1_g, enc1_be,
                f1, B,  8192, 4096, 128, 2, st, stream);
    run_layer83(f1,  128,   nullptr, 0,   enc2_w, enc2_b, enc2_g, enc2_be,
                f2, B,  4096, 2048, 256, 2, st, stream);

    // ---- fusion (banded correlation, D=5, K=3) ----
    {
        dim3 grid((2048 + 255) / 256, 11, B);
        fusion_kernel<<<grid, 256, 0, stream>>>(f2, feat, 256, 2048);
    }

    // ---- decoders: concat(A, upsample_x2(B)) handled inside the conv ----
    run_layer83(f1, 128,  feat, 11,  dec1_w, dec1_b, dec1_g, dec1_be,
                d1, B, 4096, 4096, 128, 1, st, stream);
    run_layer83(f0,  64,  d1, 128,   dec0_w, dec0_b, dec0_g, dec0_be,
                d0, B, 8192, 8192, 128, 1, st, stream);

    // ---- flow head (k=1, Cout=2) with fused transpose epilogue ----
    {
        float* ch_sum = st, *ch_sumsq = st + 256, *scale = st + 512, *shift = st + 768;
        hipMemsetAsync(st, 0, 512 * sizeof(float), stream);
        dim3 cgrid(16384 / 256, 1, B);
        conv_tiled_kernel<2, 1><<<cgrid, 256, 0, stream>>>(
            scan1, 1, d0, 128, flow_w, flow_b, fl,
            16384, 16384, 1, 0, 2, ch_sum, ch_sumsq);
        float invN = 1.0f / (float)((size_t)B * 16384);
        bn_prep_kernel<<<1, 256, 0, stream>>>(ch_sum, ch_sumsq, flow_g, flow_be,
                                              scale, shift, 2, invN);
        dim3 tgrid(16384 / 256, 1, B);
        bn_lrelu_transpose_kernel<<<tgrid, 256, 0, stream>>>(fl, scale, shift,
                                                             (float*)d_out, 16384);
    }
}

// Round 4
// 777.377 us; speedup vs baseline: 5.3229x; 1.1345x over previous
//
#include <hip/hip_runtime.h>
#include <cstddef>

#define SLOPE 0.01f
#define BN_EPS 1e-5f

__device__ __forceinline__ float lrelu_norm(float v, float sc, float sh) {
    float t = fmaf(v, sc, sh);
    return fmaxf(t, SLOPE * t);   // == lrelu(t) for slope in (0,1)
}

// ---------------------------------------------------------------------------
// Register-tiled fused Conv1d. Each thread: COT output channels x OT output
// positions. Source A read directly; source B read through x2 nearest
// upsample (idx = u>>1). Each source optionally normalized on load with the
// producer layer's BN scale/shift + LeakyReLU (null = raw). Writes RAW conv
// output (pre-BN) and accumulates per-channel sum/sumsq for this layer's BN.
// Grid: (L_out/(256*OT), Cout/COT, B).  L_out must divide exactly.
// ---------------------------------------------------------------------------
template<int COT, int K, int STRIDE, int OT>
__global__ __launch_bounds__(256) void conv_fused_kernel(
    const float* __restrict__ xA, int CA,
    const float* __restrict__ scA, const float* __restrict__ shA,
    const float* __restrict__ xB, int CB,
    const float* __restrict__ scB, const float* __restrict__ shB,
    const float* __restrict__ w, const float* __restrict__ bias,
    float* __restrict__ y,
    int L_in, int L_out, int Cout,
    float* __restrict__ ch_sum, float* __restrict__ ch_sumsq)
{
    constexpr int PAD = (K - 1) / 2;
    constexpr int NX  = (OT - 1) * STRIDE + K;   // input values per tile
    const int o0 = (blockIdx.x * 256 + threadIdx.x) * OT;
    const int cb = blockIdx.y * COT;             // wave-uniform
    const int b  = blockIdx.z;
    const int Cin = CA + CB;
    const int u0 = o0 * STRIDE - PAD;            // first needed input index

    float acc[COT][OT];
    #pragma unroll
    for (int j = 0; j < COT; ++j)
        #pragma unroll
        for (int p = 0; p < OT; ++p) acc[j][p] = 0.0f;

    const float* wbase = w + (size_t)cb * Cin * K;   // uniform -> s_loads
    const bool nA = (scA != nullptr);
    const bool nB = (scB != nullptr);

    // ---- source A ----
    for (int c = 0; c < CA; ++c) {
        const float* xp = xA + ((size_t)b * CA + c) * L_in;
        const float sc = nA ? scA[c] : 1.0f;
        const float sh = nA ? shA[c] : 0.0f;
        float xv[NX];
        if constexpr (K == 1) {
            float4 m = *(const float4*)(xp + o0);
            xv[0] = m.x; xv[1] = m.y; xv[2] = m.z; xv[3] = m.w;
            if (nA) {
                #pragma unroll
                for (int jj = 0; jj < NX; ++jj) xv[jj] = lrelu_norm(xv[jj], sc, sh);
            }
        } else if constexpr (STRIDE == 1) {
            // NX = OT + 2: [halo_l, float4, halo_r]
            float4 m = *(const float4*)(xp + o0);
            float hl = (o0 > 0)           ? xp[o0 - 1]  : 0.0f;
            float hr = (o0 + OT < L_in)   ? xp[o0 + OT] : 0.0f;
            if (nA) {
                m.x = lrelu_norm(m.x, sc, sh); m.y = lrelu_norm(m.y, sc, sh);
                m.z = lrelu_norm(m.z, sc, sh); m.w = lrelu_norm(m.w, sc, sh);
                hl = (o0 > 0)         ? lrelu_norm(hl, sc, sh) : 0.0f;
                hr = (o0 + OT < L_in) ? lrelu_norm(hr, sc, sh) : 0.0f;
            }
            xv[0] = hl; xv[1] = m.x; xv[2] = m.y; xv[3] = m.z; xv[4] = m.w;
            xv[5] = hr;
        } else { // STRIDE == 2, K == 3, OT == 4; NX = 9: [halo_l, 2 float4s]
            float4 m0 = *(const float4*)(xp + 2 * o0);
            float4 m1 = *(const float4*)(xp + 2 * o0 + 4);
            float hl = (o0 > 0) ? xp[2 * o0 - 1] : 0.0f;
            if (nA) {
                m0.x = lrelu_norm(m0.x, sc, sh); m0.y = lrelu_norm(m0.y, sc, sh);
                m0.z = lrelu_norm(m0.z, sc, sh); m0.w = lrelu_norm(m0.w, sc, sh);
                m1.x = lrelu_norm(m1.x, sc, sh); m1.y = lrelu_norm(m1.y, sc, sh);
                m1.z = lrelu_norm(m1.z, sc, sh); m1.w = lrelu_norm(m1.w, sc, sh);
                hl = (o0 > 0) ? lrelu_norm(hl, sc, sh) : 0.0f;
            }
            xv[0] = hl; xv[1] = m0.x; xv[2] = m0.y; xv[3] = m0.z; xv[4] = m0.w;
            xv[5] = m1.x; xv[6] = m1.y; xv[7] = m1.z; xv[8] = m1.w;
        }
        #pragma unroll
        for (int j = 0; j < COT; ++j) {
            const float* wr = wbase + (size_t)j * Cin * K + c * K;
            #pragma unroll
            for (int p = 0; p < OT; ++p)
                #pragma unroll
                for (int t = 0; t < K; ++t)
                    acc[j][p] = fmaf(wr[t], xv[p * STRIDE + t], acc[j][p]);
        }
    }

    // ---- source B (x2 nearest upsample) ----
    if (CB > 0) {
        const int LB = L_in >> 1;
        for (int c = 0; c < CB; ++c) {
            const float* xp = xB + ((size_t)b * CB + c) * LB;
            const float sc = nB ? scB[c] : 1.0f;
            const float sh = nB ? shB[c] : 0.0f;
            float xv[NX];
            #pragma unroll
            for (int jj = 0; jj < NX; ++jj) {
                int u = u0 + jj;
                float v = 0.0f;
                if (u >= 0 && u < L_in) {
                    v = xp[u >> 1];
                    if (nB) v = lrelu_norm(v, sc, sh);
                }
                xv[jj] = v;
            }
            #pragma unroll
            for (int j = 0; j < COT; ++j) {
                const float* wr = wbase + (size_t)j * Cin * K + (CA + c) * K;
                #pragma unroll
                for (int p = 0; p < OT; ++p)
                    #pragma unroll
                    for (int t = 0; t < K; ++t)
                        acc[j][p] = fmaf(wr[t], xv[p * STRIDE + t], acc[j][p]);
            }
        }
    }

    // ---- bias + store (raw, pre-BN); store width matches OT ----
    #pragma unroll
    for (int j = 0; j < COT; ++j) {
        float bj = bias[cb + j];
        #pragma unroll
        for (int p = 0; p < OT; ++p) acc[j][p] += bj;
        float* yp = y + ((size_t)b * Cout + cb + j) * L_out + o0;
        if constexpr (OT == 4) {
            float4 v = { acc[j][0], acc[j][1], acc[j][2], acc[j][3] };
            *(float4*)yp = v;
        } else if constexpr (OT == 2) {
            float2 v = { acc[j][0], acc[j][1] };
            *(float2*)yp = v;
        } else {
            #pragma unroll
            for (int p = 0; p < OT; ++p) yp[p] = acc[j][p];
        }
    }

    // ---- per-channel (sum, sumsq) block reduction -> atomics ----
    __shared__ float s1[4 * COT], s2[4 * COT];
    const int lane = threadIdx.x & 63;
    const int wid  = threadIdx.x >> 6;
    #pragma unroll
    for (int j = 0; j < COT; ++j) {
        float v = 0.0f, v2 = 0.0f;
        #pragma unroll
        for (int p = 0; p < OT; ++p) { v += acc[j][p]; v2 = fmaf(acc[j][p], acc[j][p], v2); }
        #pragma unroll
        for (int off = 32; off > 0; off >>= 1) {
            v  += __shfl_down(v,  off, 64);
            v2 += __shfl_down(v2, off, 64);
        }
        if (lane == 0) { s1[wid * COT + j] = v; s2[wid * COT + j] = v2; }
    }
    __syncthreads();
    if (threadIdx.x < COT) {
        int j = threadIdx.x;
        float t1 = s1[j] + s1[COT + j] + s1[2 * COT + j] + s1[3 * COT + j];
        float t2 = s2[j] + s2[COT + j] + s2[2 * COT + j] + s2[3 * COT + j];
        atomicAdd(&ch_sum[cb + j],   t1);
        atomicAdd(&ch_sumsq[cb + j], t2);
    }
}

// sum/sumsq -> per-channel affine (scale = g*rstd, shift = be - g*rstd*mean)
__global__ void bn_prep_kernel(const float* __restrict__ ch_sum,
                               const float* __restrict__ ch_sumsq,
                               const float* __restrict__ g,
                               const float* __restrict__ be,
                               float* __restrict__ scale,
                               float* __restrict__ shift,
                               int C, float invN)
{
    int c = blockIdx.x * blockDim.x + threadIdx.x;
    if (c < C) {
        float m  = ch_sum[c] * invN;
        float v  = ch_sumsq[c] * invN - m * m;   // biased variance
        float r  = rsqrtf(v + BN_EPS);
        float sc = g[c] * r;
        scale[c] = sc;
        shift[c] = be[c] - sc * m;
    }
}

// Banded correlation fusion on raw f2, BN+lrelu applied on load.
__global__ __launch_bounds__(256) void fusion_kernel(
    const float* __restrict__ f2,
    const float* __restrict__ scale, const float* __restrict__ shift,
    float* __restrict__ feat, int C, int N)
{
    const int i = blockIdx.x * blockDim.x + threadIdx.x;
    const int d = (int)blockIdx.y - 5;
    const int b = blockIdx.z;
    if (i >= N) return;
    const int i2 = min(max(i + d, 0), N - 1);
    const int a0 = max(i - 1, 0), a1 = i, a2 = min(i + 1, N - 1);
    const int b0 = max(i2 - 1, 0), b1 = i2, b2 = min(i2 + 1, N - 1);
    const float* fb = f2 + (size_t)b * C * N;
    float acc = 0.0f;
    for (int c = 0; c < C; ++c) {
        const float* fc = fb + (size_t)c * N;
        const float sc = scale[c], sh = shift[c];
        float va0 = lrelu_norm(fc[a0], sc, sh);
        float va1 = lrelu_norm(fc[a1], sc, sh);
        float va2 = lrelu_norm(fc[a2], sc, sh);
        float vb0 = lrelu_norm(fc[b0], sc, sh);
        float vb1 = lrelu_norm(fc[b1], sc, sh);
        float vb2 = lrelu_norm(fc[b2], sc, sh);
        acc = fmaf(va0, vb0, acc);
        acc = fmaf(va1, vb1, acc);
        acc = fmaf(va2, vb2, acc);
    }
    feat[((size_t)b * 11 + (d + 5)) * N + i] = acc;
}

// Flow head epilogue: normalize + lrelu + transpose (B,2,N) -> (B,N,2)
__global__ __launch_bounds__(256) void bn_lrelu_transpose_kernel(
    const float* __restrict__ y,
    const float* __restrict__ scale, const float* __restrict__ shift,
    float* __restrict__ out, int N)
{
    const int i = blockIdx.x * blockDim.x + threadIdx.x;
    const int b = blockIdx.z;
    if (i >= N) return;
    float2 v;
    v.x = lrelu_norm(y[((size_t)b * 2 + 0) * N + i], scale[0], shift[0]);
    v.y = lrelu_norm(y[((size_t)b * 2 + 1) * N + i], scale[1], shift[1]);
    *(float2*)(out + ((size_t)b * N + i) * 2) = v;
}

// ---------------------------------------------------------------------------

extern "C" void kernel_launch(void* const* d_in, const int* in_sizes, int n_in,
                              void* d_out, int out_size, void* d_ws, size_t ws_size,
                              hipStream_t stream)
{
    const int B = 8;
    const float* scan1 = (const float*)d_in[0];   // (B, N, 1) == (B, 1, N)

    const float* enc0_w = (const float*)d_in[1];
    const float* enc0_b = (const float*)d_in[2];
    const float* enc0_g = (const float*)d_in[3];
    const float* enc0_be= (const float*)d_in[4];
    const float* enc1_w = (const float*)d_in[5];
    const float* enc1_b = (const float*)d_in[6];
    const float* enc1_g = (const float*)d_in[7];
    const float* enc1_be= (const float*)d_in[8];
    const float* enc2_w = (const float*)d_in[9];
    const float* enc2_b = (const float*)d_in[10];
    const float* enc2_g = (const float*)d_in[11];
    const float* enc2_be= (const float*)d_in[12];
    const float* dec1_w = (const float*)d_in[13];
    const float* dec1_b = (const float*)d_in[14];
    const float* dec1_g = (const float*)d_in[15];
    const float* dec1_be= (const float*)d_in[16];
    const float* dec0_w = (const float*)d_in[17];
    const float* dec0_b = (const float*)d_in[18];
    const float* dec0_g = (const float*)d_in[19];
    const float* dec0_be= (const float*)d_in[20];
    const float* flow_w = (const float*)d_in[21];
    const float* flow_b = (const float*)d_in[22];
    const float* flow_g = (const float*)d_in[23];
    const float* flow_be= (const float*)d_in[24];

    float* ws = (float*)d_ws;
    const size_t off_f0   = 0;                       // (B,  64, 8192) raw
    const size_t off_f1   = off_f0  + 4194304;       // (B, 128, 4096) raw
    const size_t off_f2   = off_f1  + 4194304;       // (B, 256, 2048) raw; reused for d1
    const size_t off_feat = off_f2  + 4194304;       // (B,  11, 2048)
    const size_t off_d0   = off_feat + 180224;       // (B, 128, 8192) raw
    const size_t off_fl   = off_d0  + 8388608;       // (B,   2,16384) raw
    const size_t off_st   = off_fl  + 262144;        // 6 x 1024 stats

    float* f0   = ws + off_f0;
    float* f1   = ws + off_f1;
    float* f2   = ws + off_f2;
    float* feat = ws + off_feat;
    float* d1   = ws + off_f2;    // reuse f2's buffer after fusion
    float* d0   = ws + off_d0;
    float* fl   = ws + off_fl;

    // per-layer stats slot: [sum 256 | sumsq 256 | scale 256 | shift 256]
    float* st0 = ws + off_st;          // enc0
    float* st1 = st0 + 1024;           // enc1
    float* st2 = st1 + 1024;           // enc2
    float* st3 = st2 + 1024;           // dec1
    float* st4 = st3 + 1024;           // dec0
    float* st5 = st4 + 1024;           // flow
    hipMemsetAsync(st0, 0, 6 * 1024 * sizeof(float), stream);

    // ---- enc0: (B,1,16384) -> (B,64,8192), stride 2 ----
    {
        dim3 g(8192 / 1024, 64 / 8, B);
        conv_fused_kernel<8, 3, 2, 4><<<g, 256, 0, stream>>>(
            scan1, 1, nullptr, nullptr, nullptr, 0, nullptr, nullptr,
            enc0_w, enc0_b, f0, 16384, 8192, 64, st0, st0 + 256);
        bn_prep_kernel<<<1, 256, 0, stream>>>(st0, st0 + 256, enc0_g, enc0_be,
                                              st0 + 512, st0 + 768, 64,
                                              1.0f / (B * 8192.0f));
    }
    // ---- enc1: (B,64,8192) -> (B,128,4096), stride 2 ----
    {
        dim3 g(4096 / 1024, 128 / 8, B);
        conv_fused_kernel<8, 3, 2, 4><<<g, 256, 0, stream>>>(
            f0, 64, st0 + 512, st0 + 768, nullptr, 0, nullptr, nullptr,
            enc1_w, enc1_b, f1, 8192, 4096, 128, st1, st1 + 256);
        bn_prep_kernel<<<1, 256, 0, stream>>>(st1, st1 + 256, enc1_g, enc1_be,
                                              st1 + 512, st1 + 768, 128,
                                              1.0f / (B * 4096.0f));
    }
    // ---- enc2: (B,128,4096) -> (B,256,2048), stride 2 ----
    {
        dim3 g(2048 / 1024, 256 / 8, B);
        conv_fused_kernel<8, 3, 2, 4><<<g, 256, 0, stream>>>(
            f1, 128, st1 + 512, st1 + 768, nullptr, 0, nullptr, nullptr,
            enc2_w, enc2_b, f2, 4096, 2048, 256, st2, st2 + 256);
        bn_prep_kernel<<<1, 256, 0, stream>>>(st2, st2 + 256, enc2_g, enc2_be,
                                              st2 + 512, st2 + 768, 256,
                                              1.0f / (B * 2048.0f));
    }
    // ---- fusion (banded correlation on normalized f2) ----
    {
        dim3 g(2048 / 256, 11, B);
        fusion_kernel<<<g, 256, 0, stream>>>(f2, st2 + 512, st2 + 768, feat, 256, 2048);
    }
    // ---- dec1: concat(norm(f1), up2(feat)) -> (B,128,4096), stride 1 ----
    {
        dim3 g(4096 / 1024, 128 / 8, B);
        conv_fused_kernel<8, 3, 1, 4><<<g, 256, 0, stream>>>(
            f1, 128, st1 + 512, st1 + 768, feat, 11, nullptr, nullptr,
            dec1_w, dec1_b, d1, 4096, 4096, 128, st3, st3 + 256);
        bn_prep_kernel<<<1, 256, 0, stream>>>(st3, st3 + 256, dec1_g, dec1_be,
                                              st3 + 512, st3 + 768, 128,
                                              1.0f / (B * 4096.0f));
    }
    // ---- dec0: concat(norm(f0), up2(norm(d1))) -> (B,128,8192), stride 1 ----
    {
        dim3 g(8192 / 1024, 128 / 8, B);
        conv_fused_kernel<8, 3, 1, 4><<<g, 256, 0, stream>>>(
            f0, 64, st0 + 512, st0 + 768, d1, 128, st3 + 512, st3 + 768,
            dec0_w, dec0_b, d0, 8192, 8192, 128, st4, st4 + 256);
        bn_prep_kernel<<<1, 256, 0, stream>>>(st4, st4 + 256, dec0_g, dec0_be,
                                              st4 + 512, st4 + 768, 128,
                                              1.0f / (B * 8192.0f));
    }
    // ---- flow: concat(scan1, up2(norm(d0))) -> (B,2,16384), k=1 ----
    {
        dim3 g(16384 / 1024, 1, B);
        conv_fused_kernel<2, 1, 1, 4><<<g, 256, 0, stream>>>(
            scan1, 1, nullptr, nullptr, d0, 128, st4 + 512, st4 + 768,
            flow_w, flow_b, fl, 16384, 16384, 2, st5, st5 + 256);
        bn_prep_kernel<<<1, 256, 0, stream>>>(st5, st5 + 256, flow_g, flow_be,
                                              st5 + 512, st5 + 768, 2,
                                              1.0f / (B * 16384.0f));
    }
    // ---- output: norm + lrelu + transpose ----
    {
        dim3 g(16384 / 256, 1, B);
        bn_lrelu_transpose_kernel<<<g, 256, 0, stream>>>(fl, st5 + 512, st5 + 768,
                                                         (float*)d_out, 16384);
    }
}

// Round 5
// 701.367 us; speedup vs baseline: 5.8998x; 1.1084x over previous
//
#include <hip/hip_runtime.h>
#include <cstddef>

#define SLOPE 0.01f
#define BN_EPS 1e-5f

__device__ __forceinline__ float lrelu_norm(float v, float sc, float sh) {
    float t = fmaf(v, sc, sh);
    return fmaxf(t, SLOPE * t);   // == lrelu(t) for slope in (0,1)
}

// Compute BN affine (scale, shift) for channel c from raw sums.
// st layout: [sum(256) | sumsq(256)].
__device__ __forceinline__ void bn_coeff(const float* __restrict__ st,
                                         const float* __restrict__ g,
                                         const float* __restrict__ be,
                                         float invN, int c,
                                         float& sc, float& sh) {
    float m   = st[c] * invN;
    float var = fmaf(st[256 + c], invN, -m * m);   // biased variance
    float r   = rsqrtf(var + BN_EPS);
    sc = g[c] * r;
    sh = fmaf(-sc, m, be[c]);
}

// ---------------------------------------------------------------------------
// Register-tiled fused Conv1d. Each thread: COT output channels x OT=4 output
// positions. Source A read directly; source B read through x2 nearest
// upsample (idx = u>>1, only 4 distinct source values per tile -> float2 + 2
// scalars). Each source optionally BN+LeakyReLU-normalized on load using the
// PRODUCER layer's raw (sum,sumsq) + (g,be), computed inline (stX==null =
// raw). Writes RAW conv output (pre-BN) and accumulates this layer's per-
// channel sum/sumsq. Grid: (L_out/(256*OT), Cout/COT, B). Exact division.
// ---------------------------------------------------------------------------
template<int COT, int K, int STRIDE, int OT>
__global__ __launch_bounds__(256) void conv_fused_kernel(
    const float* __restrict__ xA, int CA,
    const float* __restrict__ stA, const float* __restrict__ gA,
    const float* __restrict__ beA, float invNA,
    const float* __restrict__ xB, int CB,
    const float* __restrict__ stB, const float* __restrict__ gB,
    const float* __restrict__ beB, float invNB,
    const float* __restrict__ w, const float* __restrict__ bias,
    float* __restrict__ y,
    int L_in, int L_out, int Cout,
    float* __restrict__ ch_sum, float* __restrict__ ch_sumsq)
{
    constexpr int PAD = (K - 1) / 2;
    constexpr int NX  = (OT - 1) * STRIDE + K;   // input values per tile
    const int o0 = (blockIdx.x * 256 + threadIdx.x) * OT;
    const int cb = blockIdx.y * COT;             // wave-uniform
    const int b  = blockIdx.z;
    const int Cin = CA + CB;

    float acc[COT][OT];
    #pragma unroll
    for (int j = 0; j < COT; ++j)
        #pragma unroll
        for (int p = 0; p < OT; ++p) acc[j][p] = 0.0f;

    const float* wbase = w + (size_t)cb * Cin * K;   // uniform -> s_loads
    const bool nA = (stA != nullptr);
    const bool nB = (stB != nullptr);

    // ---- source A (direct) ----
    #pragma unroll 2
    for (int c = 0; c < CA; ++c) {
        const float* xp = xA + ((size_t)b * CA + c) * L_in;
        float sc = 1.0f, sh = 0.0f;
        if (nA) bn_coeff(stA, gA, beA, invNA, c, sc, sh);
        float xv[NX];
        if constexpr (K == 1) {
            float4 m = *(const float4*)(xp + o0);
            xv[0] = m.x; xv[1] = m.y; xv[2] = m.z; xv[3] = m.w;
            if (nA) {
                #pragma unroll
                for (int jj = 0; jj < NX; ++jj) xv[jj] = lrelu_norm(xv[jj], sc, sh);
            }
        } else if constexpr (STRIDE == 1) {
            // NX = OT + 2: [halo_l, float4, halo_r]
            float4 m = *(const float4*)(xp + o0);
            float hl = (o0 > 0)         ? xp[o0 - 1]  : 0.0f;
            float hr = (o0 + OT < L_in) ? xp[o0 + OT] : 0.0f;
            if (nA) {
                m.x = lrelu_norm(m.x, sc, sh); m.y = lrelu_norm(m.y, sc, sh);
                m.z = lrelu_norm(m.z, sc, sh); m.w = lrelu_norm(m.w, sc, sh);
                hl = (o0 > 0)         ? lrelu_norm(hl, sc, sh) : 0.0f;
                hr = (o0 + OT < L_in) ? lrelu_norm(hr, sc, sh) : 0.0f;
            }
            xv[0] = hl; xv[1] = m.x; xv[2] = m.y; xv[3] = m.z; xv[4] = m.w;
            xv[5] = hr;
        } else { // STRIDE == 2, K == 3, OT == 4; NX = 9: [halo_l, 2 float4s]
            float4 m0 = *(const float4*)(xp + 2 * o0);
            float4 m1 = *(const float4*)(xp + 2 * o0 + 4);
            float hl = (o0 > 0) ? xp[2 * o0 - 1] : 0.0f;
            if (nA) {
                m0.x = lrelu_norm(m0.x, sc, sh); m0.y = lrelu_norm(m0.y, sc, sh);
                m0.z = lrelu_norm(m0.z, sc, sh); m0.w = lrelu_norm(m0.w, sc, sh);
                m1.x = lrelu_norm(m1.x, sc, sh); m1.y = lrelu_norm(m1.y, sc, sh);
                m1.z = lrelu_norm(m1.z, sc, sh); m1.w = lrelu_norm(m1.w, sc, sh);
                hl = (o0 > 0) ? lrelu_norm(hl, sc, sh) : 0.0f;
            }
            xv[0] = hl; xv[1] = m0.x; xv[2] = m0.y; xv[3] = m0.z; xv[4] = m0.w;
            xv[5] = m1.x; xv[6] = m1.y; xv[7] = m1.z; xv[8] = m1.w;
        }
        #pragma unroll
        for (int j = 0; j < COT; ++j) {
            const float* wr = wbase + (size_t)j * Cin * K + c * K;
            #pragma unroll
            for (int p = 0; p < OT; ++p)
                #pragma unroll
                for (int t = 0; t < K; ++t)
                    acc[j][p] = fmaf(wr[t], xv[p * STRIDE + t], acc[j][p]);
        }
    }

    // ---- source B (x2 nearest upsample; STRIDE==1 only) ----
    if (CB > 0) {
        static_assert(STRIDE == 1 || true, "");
        const int s0 = o0 >> 1;                 // even, 8B-aligned
        #pragma unroll 2
        for (int c = 0; c < CB; ++c) {
            const float* xp = xB + ((size_t)b * CB + c) * (L_in >> 1);
            float sc = 1.0f, sh = 0.0f;
            if (nB) bn_coeff(stB, gB, beB, invNB, c, sc, sh);
            float xv[NX];
            if constexpr (K == 1) {
                // u = o0..o0+3 -> s = {s0, s0, s0+1, s0+1}
                float2 m = *(const float2*)(xp + s0);
                float v0 = m.x, v1 = m.y;
                if (nB) { v0 = lrelu_norm(v0, sc, sh); v1 = lrelu_norm(v1, sc, sh); }
                xv[0] = v0; xv[1] = v0; xv[2] = v1; xv[3] = v1;
            } else {
                // K==3: u = o0-1 .. o0+4 -> s = {s0-1, s0, s0, s0+1, s0+1, s0+2}
                float2 m = *(const float2*)(xp + s0);
                float vl = (o0 > 0)         ? xp[s0 - 1] : 0.0f;
                float vr = (o0 + OT < L_in) ? xp[s0 + 2] : 0.0f;
                float v0 = m.x, v1 = m.y;
                if (nB) {
                    v0 = lrelu_norm(v0, sc, sh); v1 = lrelu_norm(v1, sc, sh);
                    vl = (o0 > 0)         ? lrelu_norm(vl, sc, sh) : 0.0f;
                    vr = (o0 + OT < L_in) ? lrelu_norm(vr, sc, sh) : 0.0f;
                }
                xv[0] = vl; xv[1] = v0; xv[2] = v0; xv[3] = v1; xv[4] = v1;
                xv[5] = vr;
            }
            #pragma unroll
            for (int j = 0; j < COT; ++j) {
                const float* wr = wbase + (size_t)j * Cin * K + (CA + c) * K;
                #pragma unroll
                for (int p = 0; p < OT; ++p)
                    #pragma unroll
                    for (int t = 0; t < K; ++t)
                        acc[j][p] = fmaf(wr[t], xv[p * STRIDE + t], acc[j][p]);
            }
        }
    }

    // ---- bias + store (raw, pre-BN) ----
    #pragma unroll
    for (int j = 0; j < COT; ++j) {
        float bj = bias[cb + j];
        #pragma unroll
        for (int p = 0; p < OT; ++p) acc[j][p] += bj;
        float* yp = y + ((size_t)b * Cout + cb + j) * L_out + o0;
        if constexpr (OT == 4) {
            float4 v = { acc[j][0], acc[j][1], acc[j][2], acc[j][3] };
            *(float4*)yp = v;
        } else {
            #pragma unroll
            for (int p = 0; p < OT; ++p) yp[p] = acc[j][p];
        }
    }

    // ---- per-channel (sum, sumsq) block reduction -> atomics ----
    __shared__ float s1[4 * COT], s2[4 * COT];
    const int lane = threadIdx.x & 63;
    const int wid  = threadIdx.x >> 6;
    #pragma unroll
    for (int j = 0; j < COT; ++j) {
        float v = 0.0f, v2 = 0.0f;
        #pragma unroll
        for (int p = 0; p < OT; ++p) { v += acc[j][p]; v2 = fmaf(acc[j][p], acc[j][p], v2); }
        #pragma unroll
        for (int off = 32; off > 0; off >>= 1) {
            v  += __shfl_down(v,  off, 64);
            v2 += __shfl_down(v2, off, 64);
        }
        if (lane == 0) { s1[wid * COT + j] = v; s2[wid * COT + j] = v2; }
    }
    __syncthreads();
    if (threadIdx.x < COT) {
        int j = threadIdx.x;
        float t1 = s1[j] + s1[COT + j] + s1[2 * COT + j] + s1[3 * COT + j];
        float t2 = s2[j] + s2[COT + j] + s2[2 * COT + j] + s2[3 * COT + j];
        atomicAdd(&ch_sum[cb + j],   t1);
        atomicAdd(&ch_sumsq[cb + j], t2);
    }
}

// Banded correlation fusion on raw f2, BN+lrelu applied on load (inline BN).
__global__ __launch_bounds__(256) void fusion_kernel(
    const float* __restrict__ f2,
    const float* __restrict__ st, const float* __restrict__ g,
    const float* __restrict__ be, float invN,
    float* __restrict__ feat, int C, int N)
{
    const int i = blockIdx.x * blockDim.x + threadIdx.x;
    const int d = (int)blockIdx.y - 5;
    const int b = blockIdx.z;
    if (i >= N) return;
    const int i2 = min(max(i + d, 0), N - 1);
    const int a0 = max(i - 1, 0), a1 = i, a2 = min(i + 1, N - 1);
    const int b0 = max(i2 - 1, 0), b1 = i2, b2 = min(i2 + 1, N - 1);
    const float* fb = f2 + (size_t)b * C * N;
    float acc = 0.0f;
    for (int c = 0; c < C; ++c) {
        const float* fc = fb + (size_t)c * N;
        float sc, sh;
        bn_coeff(st, g, be, invN, c, sc, sh);
        float va0 = lrelu_norm(fc[a0], sc, sh);
        float va1 = lrelu_norm(fc[a1], sc, sh);
        float va2 = lrelu_norm(fc[a2], sc, sh);
        float vb0 = lrelu_norm(fc[b0], sc, sh);
        float vb1 = lrelu_norm(fc[b1], sc, sh);
        float vb2 = lrelu_norm(fc[b2], sc, sh);
        acc = fmaf(va0, vb0, acc);
        acc = fmaf(va1, vb1, acc);
        acc = fmaf(va2, vb2, acc);
    }
    feat[((size_t)b * 11 + (d + 5)) * N + i] = acc;
}

// Flow head epilogue: normalize + lrelu + transpose (B,2,N) -> (B,N,2)
__global__ __launch_bounds__(256) void bn_lrelu_transpose_kernel(
    const float* __restrict__ y,
    const float* __restrict__ st, const float* __restrict__ g,
    const float* __restrict__ be, float invN,
    float* __restrict__ out, int N)
{
    const int i = blockIdx.x * blockDim.x + threadIdx.x;
    const int b = blockIdx.z;
    if (i >= N) return;
    float sc0, sh0, sc1, sh1;
    bn_coeff(st, g, be, invN, 0, sc0, sh0);
    bn_coeff(st, g, be, invN, 1, sc1, sh1);
    float2 v;
    v.x = lrelu_norm(y[((size_t)b * 2 + 0) * N + i], sc0, sh0);
    v.y = lrelu_norm(y[((size_t)b * 2 + 1) * N + i], sc1, sh1);
    *(float2*)(out + ((size_t)b * N + i) * 2) = v;
}

// ---------------------------------------------------------------------------

extern "C" void kernel_launch(void* const* d_in, const int* in_sizes, int n_in,
                              void* d_out, int out_size, void* d_ws, size_t ws_size,
                              hipStream_t stream)
{
    const int B = 8;
    const float* scan1 = (const float*)d_in[0];   // (B, N, 1) == (B, 1, N)

    const float* enc0_w = (const float*)d_in[1];
    const float* enc0_b = (const float*)d_in[2];
    const float* enc0_g = (const float*)d_in[3];
    const float* enc0_be= (const float*)d_in[4];
    const float* enc1_w = (const float*)d_in[5];
    const float* enc1_b = (const float*)d_in[6];
    const float* enc1_g = (const float*)d_in[7];
    const float* enc1_be= (const float*)d_in[8];
    const float* enc2_w = (const float*)d_in[9];
    const float* enc2_b = (const float*)d_in[10];
    const float* enc2_g = (const float*)d_in[11];
    const float* enc2_be= (const float*)d_in[12];
    const float* dec1_w = (const float*)d_in[13];
    const float* dec1_b = (const float*)d_in[14];
    const float* dec1_g = (const float*)d_in[15];
    const float* dec1_be= (const float*)d_in[16];
    const float* dec0_w = (const float*)d_in[17];
    const float* dec0_b = (const float*)d_in[18];
    const float* dec0_g = (const float*)d_in[19];
    const float* dec0_be= (const float*)d_in[20];
    const float* flow_w = (const float*)d_in[21];
    const float* flow_b = (const float*)d_in[22];
    const float* flow_g = (const float*)d_in[23];
    const float* flow_be= (const float*)d_in[24];

    float* ws = (float*)d_ws;
    const size_t off_f0   = 0;                       // (B,  64, 8192) raw
    const size_t off_f1   = off_f0  + 4194304;       // (B, 128, 4096) raw
    const size_t off_f2   = off_f1  + 4194304;       // (B, 256, 2048) raw; reused for d1
    const size_t off_feat = off_f2  + 4194304;       // (B,  11, 2048)
    const size_t off_d0   = off_feat + 180224;       // (B, 128, 8192) raw
    const size_t off_fl   = off_d0  + 8388608;       // (B,   2,16384) raw
    const size_t off_st   = off_fl  + 262144;        // 6 x 512 stats

    float* f0   = ws + off_f0;
    float* f1   = ws + off_f1;
    float* f2   = ws + off_f2;
    float* feat = ws + off_feat;
    float* d1   = ws + off_f2;    // reuse f2's buffer after fusion
    float* d0   = ws + off_d0;
    float* fl   = ws + off_fl;

    // per-layer stats slot: [sum 256 | sumsq 256]
    float* st0 = ws + off_st;          // enc0
    float* st1 = st0 + 512;            // enc1
    float* st2 = st1 + 512;            // enc2
    float* st3 = st2 + 512;            // dec1
    float* st4 = st3 + 512;            // dec0
    float* st5 = st4 + 512;            // flow
    hipMemsetAsync(st0, 0, 6 * 512 * sizeof(float), stream);

    const float iN0 = 1.0f / (B * 8192.0f);   // enc0 out
    const float iN1 = 1.0f / (B * 4096.0f);   // enc1 out
    const float iN2 = 1.0f / (B * 2048.0f);   // enc2 out
    const float iN3 = 1.0f / (B * 4096.0f);   // dec1 out
    const float iN4 = 1.0f / (B * 8192.0f);   // dec0 out
    const float iN5 = 1.0f / (B * 16384.0f);  // flow out

    // ---- enc0: (B,1,16384) -> (B,64,8192), stride 2, raw input ----
    {
        dim3 g(8192 / 1024, 64 / 8, B);
        conv_fused_kernel<8, 3, 2, 4><<<g, 256, 0, stream>>>(
            scan1, 1, nullptr, nullptr, nullptr, 0.0f,
            nullptr, 0, nullptr, nullptr, nullptr, 0.0f,
            enc0_w, enc0_b, f0, 16384, 8192, 64, st0, st0 + 256);
    }
    // ---- enc1: norm(f0) -> (B,128,4096), stride 2 ----
    {
        dim3 g(4096 / 1024, 128 / 8, B);
        conv_fused_kernel<8, 3, 2, 4><<<g, 256, 0, stream>>>(
            f0, 64, st0, enc0_g, enc0_be, iN0,
            nullptr, 0, nullptr, nullptr, nullptr, 0.0f,
            enc1_w, enc1_b, f1, 8192, 4096, 128, st1, st1 + 256);
    }
    // ---- enc2: norm(f1) -> (B,256,2048), stride 2 ----
    {
        dim3 g(2048 / 1024, 256 / 8, B);
        conv_fused_kernel<8, 3, 2, 4><<<g, 256, 0, stream>>>(
            f1, 128, st1, enc1_g, enc1_be, iN1,
            nullptr, 0, nullptr, nullptr, nullptr, 0.0f,
            enc2_w, enc2_b, f2, 4096, 2048, 256, st2, st2 + 256);
    }
    // ---- fusion: banded correlation on norm(f2) ----
    {
        dim3 g(2048 / 256, 11, B);
        fusion_kernel<<<g, 256, 0, stream>>>(f2, st2, enc2_g, enc2_be, iN2,
                                             feat, 256, 2048);
    }
    // ---- dec1: concat(norm(f1), up2(feat)) -> (B,128,4096), stride 1 ----
    {
        dim3 g(4096 / 1024, 128 / 8, B);
        conv_fused_kernel<8, 3, 1, 4><<<g, 256, 0, stream>>>(
            f1, 128, st1, enc1_g, enc1_be, iN1,
            feat, 11, nullptr, nullptr, nullptr, 0.0f,
            dec1_w, dec1_b, d1, 4096, 4096, 128, st3, st3 + 256);
    }
    // ---- dec0: concat(norm(f0), up2(norm(d1))) -> (B,128,8192), stride 1 ----
    {
        dim3 g(8192 / 1024, 128 / 8, B);
        conv_fused_kernel<8, 3, 1, 4><<<g, 256, 0, stream>>>(
            f0, 64, st0, enc0_g, enc0_be, iN0,
            d1, 128, st3, dec1_g, dec1_be, iN3,
            dec0_w, dec0_b, d0, 8192, 8192, 128, st4, st4 + 256);
    }
    // ---- flow: concat(scan1, up2(norm(d0))) -> (B,2,16384), k=1 ----
    {
        dim3 g(16384 / 1024, 1, B);
        conv_fused_kernel<2, 1, 1, 4><<<g, 256, 0, stream>>>(
            scan1, 1, nullptr, nullptr, nullptr, 0.0f,
            d0, 128, st4, dec0_g, dec0_be, iN4,
            flow_w, flow_b, fl, 16384, 16384, 2, st5, st5 + 256);
    }
    // ---- output: norm + lrelu + transpose ----
    {
        dim3 g(16384 / 256, 1, B);
        bn_lrelu_transpose_kernel<<<g, 256, 0, stream>>>(fl, st5, flow_g, flow_be,
                                                         iN5, (float*)d_out, 16384);
    }
}

// Round 6
// 654.953 us; speedup vs baseline: 6.3179x; 1.0709x over previous
//
#include <hip/hip_runtime.h>
#include <cstddef>

#define SLOPE 0.01f
#define BN_EPS 1e-5f

__device__ __forceinline__ float lrelu(float t) {
    return fmaxf(t, SLOPE * t);
}

// BN affine (scale, shift) for channel c from raw sums. st: [sum(256)|sumsq(256)].
__device__ __forceinline__ void bn_coeff(const float* __restrict__ st,
                                         const float* __restrict__ g,
                                         const float* __restrict__ be,
                                         float invN, int c,
                                         float& sc, float& sh) {
    float m   = st[c] * invN;
    float var = fmaf(st[256 + c], invN, -m * m);   // biased variance
    float r   = rsqrtf(var + BN_EPS);
    sc = g[c] * r;
    sh = fmaf(-sc, m, be[c]);
}

// ---------------------------------------------------------------------------
// Register-tiled Conv1d on pre-normalized inputs. Each thread: COT output
// channels x OT=4 positions. Source B is read through x2 nearest upsample
// (only OT/2+K-1 distinct values per tile -> float2 + scalars). Writes RAW
// conv output (pre-BN) + accumulates per-channel sum/sumsq for this layer's
// BN. Grid: (L_out/(256*OT), Cout/COT, B). Exact division required.
// ---------------------------------------------------------------------------
template<int COT, int K, int STRIDE, int OT>
__global__ __launch_bounds__(256) void conv_kernel(
    const float* __restrict__ xA, int CA,
    const float* __restrict__ xB, int CB,
    const float* __restrict__ w, const float* __restrict__ bias,
    float* __restrict__ y,
    int L_in, int L_out, int Cout,
    float* __restrict__ ch_sum, float* __restrict__ ch_sumsq)
{
    constexpr int NX = (OT - 1) * STRIDE + K;    // input values per tile
    const int o0 = (blockIdx.x * 256 + threadIdx.x) * OT;
    const int cb = blockIdx.y * COT;             // wave-uniform
    const int b  = blockIdx.z;
    const int Cin = CA + CB;

    float acc[COT][OT];
    #pragma unroll
    for (int j = 0; j < COT; ++j)
        #pragma unroll
        for (int p = 0; p < OT; ++p) acc[j][p] = 0.0f;

    const float* wbase = w + (size_t)cb * Cin * K;   // uniform -> s_loads

    // ---- source A (direct) ----
    #pragma unroll 2
    for (int c = 0; c < CA; ++c) {
        const float* xp = xA + ((size_t)b * CA + c) * L_in;
        float xv[NX];
        if constexpr (K == 1) {
            float4 m = *(const float4*)(xp + o0);
            xv[0] = m.x; xv[1] = m.y; xv[2] = m.z; xv[3] = m.w;
        } else if constexpr (STRIDE == 1) {
            // NX = OT + 2: [halo_l, float4, halo_r]
            float4 m = *(const float4*)(xp + o0);
            xv[0] = (o0 > 0)         ? xp[o0 - 1]  : 0.0f;
            xv[1] = m.x; xv[2] = m.y; xv[3] = m.z; xv[4] = m.w;
            xv[5] = (o0 + OT < L_in) ? xp[o0 + OT] : 0.0f;
        } else { // STRIDE == 2, K == 3, OT == 4; NX = 9: [halo_l, 2 float4s]
            float4 m0 = *(const float4*)(xp + 2 * o0);
            float4 m1 = *(const float4*)(xp + 2 * o0 + 4);
            xv[0] = (o0 > 0) ? xp[2 * o0 - 1] : 0.0f;
            xv[1] = m0.x; xv[2] = m0.y; xv[3] = m0.z; xv[4] = m0.w;
            xv[5] = m1.x; xv[6] = m1.y; xv[7] = m1.z; xv[8] = m1.w;
        }
        #pragma unroll
        for (int j = 0; j < COT; ++j) {
            const float* wr = wbase + (size_t)j * Cin * K + c * K;
            #pragma unroll
            for (int p = 0; p < OT; ++p)
                #pragma unroll
                for (int t = 0; t < K; ++t)
                    acc[j][p] = fmaf(wr[t], xv[p * STRIDE + t], acc[j][p]);
        }
    }

    // ---- source B (x2 nearest upsample; STRIDE==1 only) ----
    if (CB > 0) {
        const int s0 = o0 >> 1;                  // even -> 8B-aligned
        #pragma unroll 2
        for (int c = 0; c < CB; ++c) {
            const float* xp = xB + ((size_t)b * CB + c) * (L_in >> 1);
            float xv[NX];
            float2 m = *(const float2*)(xp + s0);
            if constexpr (K == 1) {
                // u = o0..o0+3 -> s = {s0, s0, s0+1, s0+1}
                xv[0] = m.x; xv[1] = m.x; xv[2] = m.y; xv[3] = m.y;
            } else {
                // K==3: u = o0-1..o0+4 -> s = {s0-1, s0, s0, s0+1, s0+1, s0+2}
                xv[0] = (o0 > 0)         ? xp[s0 - 1] : 0.0f;
                xv[1] = m.x; xv[2] = m.x; xv[3] = m.y; xv[4] = m.y;
                xv[5] = (o0 + OT < L_in) ? xp[s0 + 2] : 0.0f;
            }
            #pragma unroll
            for (int j = 0; j < COT; ++j) {
                const float* wr = wbase + (size_t)j * Cin * K + (CA + c) * K;
                #pragma unroll
                for (int p = 0; p < OT; ++p)
                    #pragma unroll
                    for (int t = 0; t < K; ++t)
                        acc[j][p] = fmaf(wr[t], xv[p * STRIDE + t], acc[j][p]);
            }
        }
    }

    // ---- bias + store (raw, pre-BN) ----
    #pragma unroll
    for (int j = 0; j < COT; ++j) {
        float bj = bias[cb + j];
        #pragma unroll
        for (int p = 0; p < OT; ++p) acc[j][p] += bj;
        float* yp = y + ((size_t)b * Cout + cb + j) * L_out + o0;
        float4 v = { acc[j][0], acc[j][1], acc[j][2], acc[j][3] };
        *(float4*)yp = v;
    }

    // ---- per-channel (sum, sumsq) block reduction -> atomics ----
    __shared__ float s1[4 * COT], s2[4 * COT];
    const int lane = threadIdx.x & 63;
    const int wid  = threadIdx.x >> 6;
    #pragma unroll
    for (int j = 0; j < COT; ++j) {
        float v = 0.0f, v2 = 0.0f;
        #pragma unroll
        for (int p = 0; p < OT; ++p) { v += acc[j][p]; v2 = fmaf(acc[j][p], acc[j][p], v2); }
        #pragma unroll
        for (int off = 32; off > 0; off >>= 1) {
            v  += __shfl_down(v,  off, 64);
            v2 += __shfl_down(v2, off, 64);
        }
        if (lane == 0) { s1[wid * COT + j] = v; s2[wid * COT + j] = v2; }
    }
    __syncthreads();
    if (threadIdx.x < COT) {
        int j = threadIdx.x;
        float t1 = s1[j] + s1[COT + j] + s1[2 * COT + j] + s1[3 * COT + j];
        float t2 = s2[j] + s2[COT + j] + s2[2 * COT + j] + s2[3 * COT + j];
        atomicAdd(&ch_sum[cb + j],   t1);
        atomicAdd(&ch_sumsq[cb + j], t2);
    }
}

// In-place y = lrelu(sc*y + sh), coeffs from raw sums, float4.
// Grid: (L/1024, C, B).
__global__ __launch_bounds__(256) void bn_lrelu_kernel(
    float* __restrict__ y,
    const float* __restrict__ st, const float* __restrict__ g,
    const float* __restrict__ be, float invN, int L4)
{
    const int c = blockIdx.y;
    const int b = blockIdx.z;
    const int C = gridDim.y;
    float sc, sh;
    bn_coeff(st, g, be, invN, c, sc, sh);
    const int o = blockIdx.x * 256 + threadIdx.x;
    if (o < L4) {
        float4* yp = (float4*)(y + ((size_t)b * C + c) * (size_t)L4 * 4);
        float4 v = yp[o];
        v.x = lrelu(fmaf(v.x, sc, sh));
        v.y = lrelu(fmaf(v.y, sc, sh));
        v.z = lrelu(fmaf(v.z, sc, sh));
        v.w = lrelu(fmaf(v.w, sc, sh));
        yp[o] = v;
    }
}

// Banded correlation fusion on normalized f2. feat[b,d+5,i].
__global__ __launch_bounds__(256) void fusion_kernel(
    const float* __restrict__ f2, float* __restrict__ feat, int C, int N)
{
    const int i = blockIdx.x * blockDim.x + threadIdx.x;
    const int d = (int)blockIdx.y - 5;
    const int b = blockIdx.z;
    if (i >= N) return;
    const int i2 = min(max(i + d, 0), N - 1);
    const int a0 = max(i - 1, 0), a1 = i, a2 = min(i + 1, N - 1);
    const int b0 = max(i2 - 1, 0), b1 = i2, b2 = min(i2 + 1, N - 1);
    const float* fb = f2 + (size_t)b * C * N;
    float acc = 0.0f;
    #pragma unroll 2
    for (int c = 0; c < C; ++c) {
        const float* fc = fb + (size_t)c * N;
        acc = fmaf(fc[a0], fc[b0], acc);
        acc = fmaf(fc[a1], fc[b1], acc);
        acc = fmaf(fc[a2], fc[b2], acc);
    }
    feat[((size_t)b * 11 + (d + 5)) * N + i] = acc;
}

// Flow head epilogue: normalize + lrelu + transpose (B,2,N) -> (B,N,2)
__global__ __launch_bounds__(256) void bn_lrelu_transpose_kernel(
    const float* __restrict__ y,
    const float* __restrict__ st, const float* __restrict__ g,
    const float* __restrict__ be, float invN,
    float* __restrict__ out, int N)
{
    const int i = blockIdx.x * blockDim.x + threadIdx.x;
    const int b = blockIdx.z;
    if (i >= N) return;
    float sc0, sh0, sc1, sh1;
    bn_coeff(st, g, be, invN, 0, sc0, sh0);
    bn_coeff(st, g, be, invN, 1, sc1, sh1);
    float2 v;
    v.x = lrelu(fmaf(y[((size_t)b * 2 + 0) * N + i], sc0, sh0));
    v.y = lrelu(fmaf(y[((size_t)b * 2 + 1) * N + i], sc1, sh1));
    *(float2*)(out + ((size_t)b * N + i) * 2) = v;
}

// ---------------------------------------------------------------------------

extern "C" void kernel_launch(void* const* d_in, const int* in_sizes, int n_in,
                              void* d_out, int out_size, void* d_ws, size_t ws_size,
                              hipStream_t stream)
{
    const int B = 8;
    const float* scan1 = (const float*)d_in[0];   // (B, N, 1) == (B, 1, N)

    const float* enc0_w = (const float*)d_in[1];
    const float* enc0_b = (const float*)d_in[2];
    const float* enc0_g = (const float*)d_in[3];
    const float* enc0_be= (const float*)d_in[4];
    const float* enc1_w = (const float*)d_in[5];
    const float* enc1_b = (const float*)d_in[6];
    const float* enc1_g = (const float*)d_in[7];
    const float* enc1_be= (const float*)d_in[8];
    const float* enc2_w = (const float*)d_in[9];
    const float* enc2_b = (const float*)d_in[10];
    const float* enc2_g = (const float*)d_in[11];
    const float* enc2_be= (const float*)d_in[12];
    const float* dec1_w = (const float*)d_in[13];
    const float* dec1_b = (const float*)d_in[14];
    const float* dec1_g = (const float*)d_in[15];
    const float* dec1_be= (const float*)d_in[16];
    const float* dec0_w = (const float*)d_in[17];
    const float* dec0_b = (const float*)d_in[18];
    const float* dec0_g = (const float*)d_in[19];
    const float* dec0_be= (const float*)d_in[20];
    const float* flow_w = (const float*)d_in[21];
    const float* flow_b = (const float*)d_in[22];
    const float* flow_g = (const float*)d_in[23];
    const float* flow_be= (const float*)d_in[24];

    float* ws = (float*)d_ws;
    const size_t off_f0   = 0;                       // (B,  64, 8192)
    const size_t off_f1   = off_f0  + 4194304;       // (B, 128, 4096)
    const size_t off_f2   = off_f1  + 4194304;       // (B, 256, 2048); reused for d1
    const size_t off_feat = off_f2  + 4194304;       // (B,  11, 2048)
    const size_t off_d0   = off_feat + 180224;       // (B, 128, 8192)
    const size_t off_fl   = off_d0  + 8388608;       // (B,   2,16384)
    const size_t off_st   = off_fl  + 262144;        // 6 x 512 stats

    float* f0   = ws + off_f0;
    float* f1   = ws + off_f1;
    float* f2   = ws + off_f2;
    float* feat = ws + off_feat;
    float* d1   = ws + off_f2;    // reuse f2's buffer after fusion
    float* d0   = ws + off_d0;
    float* fl   = ws + off_fl;

    // per-layer stats slot: [sum 256 | sumsq 256]
    float* st0 = ws + off_st;          // enc0
    float* st1 = st0 + 512;            // enc1
    float* st2 = st1 + 512;            // enc2
    float* st3 = st2 + 512;            // dec1
    float* st4 = st3 + 512;            // dec0
    float* st5 = st4 + 512;            // flow
    hipMemsetAsync(st0, 0, 6 * 512 * sizeof(float), stream);

    const float iN0 = 1.0f / (B * 8192.0f);
    const float iN1 = 1.0f / (B * 4096.0f);
    const float iN2 = 1.0f / (B * 2048.0f);
    const float iN3 = 1.0f / (B * 4096.0f);
    const float iN4 = 1.0f / (B * 8192.0f);
    const float iN5 = 1.0f / (B * 16384.0f);

    // ---- enc0: (B,1,16384) -> (B,64,8192), stride 2 ----
    conv_kernel<4, 3, 2, 4><<<dim3(8, 16, B), 256, 0, stream>>>(
        scan1, 1, nullptr, 0, enc0_w, enc0_b, f0, 16384, 8192, 64, st0, st0 + 256);
    bn_lrelu_kernel<<<dim3(8, 64, B), 256, 0, stream>>>(f0, st0, enc0_g, enc0_be, iN0, 2048);

    // ---- enc1: f0n -> (B,128,4096), stride 2 ----
    conv_kernel<4, 3, 2, 4><<<dim3(4, 32, B), 256, 0, stream>>>(
        f0, 64, nullptr, 0, enc1_w, enc1_b, f1, 8192, 4096, 128, st1, st1 + 256);
    bn_lrelu_kernel<<<dim3(4, 128, B), 256, 0, stream>>>(f1, st1, enc1_g, enc1_be, iN1, 1024);

    // ---- enc2: f1n -> (B,256,2048), stride 2 ----
    conv_kernel<4, 3, 2, 4><<<dim3(2, 64, B), 256, 0, stream>>>(
        f1, 128, nullptr, 0, enc2_w, enc2_b, f2, 4096, 2048, 256, st2, st2 + 256);
    bn_lrelu_kernel<<<dim3(2, 256, B), 256, 0, stream>>>(f2, st2, enc2_g, enc2_be, iN2, 512);

    // ---- fusion: banded correlation on f2n ----
    fusion_kernel<<<dim3(8, 11, B), 256, 0, stream>>>(f2, feat, 256, 2048);

    // ---- dec1: concat(f1n, up2(feat)) -> (B,128,4096), stride 1 ----
    conv_kernel<4, 3, 1, 4><<<dim3(4, 32, B), 256, 0, stream>>>(
        f1, 128, feat, 11, dec1_w, dec1_b, d1, 4096, 4096, 128, st3, st3 + 256);
    bn_lrelu_kernel<<<dim3(4, 128, B), 256, 0, stream>>>(d1, st3, dec1_g, dec1_be, iN3, 1024);

    // ---- dec0: concat(f0n, up2(d1n)) -> (B,128,8192), stride 1 ----
    conv_kernel<4, 3, 1, 4><<<dim3(8, 32, B), 256, 0, stream>>>(
        f0, 64, d1, 128, dec0_w, dec0_b, d0, 8192, 8192, 128, st4, st4 + 256);
    bn_lrelu_kernel<<<dim3(8, 128, B), 256, 0, stream>>>(d0, st4, dec0_g, dec0_be, iN4, 2048);

    // ---- flow: concat(scan1, up2(d0n)) -> (B,2,16384), k=1 ----
    conv_kernel<2, 1, 1, 4><<<dim3(16, 1, B), 256, 0, stream>>>(
        scan1, 1, d0, 128, flow_w, flow_b, fl, 16384, 16384, 2, st5, st5 + 256);

    // ---- output: norm + lrelu + transpose ----
    bn_lrelu_transpose_kernel<<<dim3(64, 1, B), 256, 0, stream>>>(
        fl, st5, flow_g, flow_be, iN5, (float*)d_out, 16384);
}

// Round 7
// 326.090 us; speedup vs baseline: 12.6896x; 2.0085x over previous
//
#include <hip/hip_runtime.h>
#include <cstddef>

#define SLOPE 0.01f
#define BN_EPS 1e-5f

typedef __attribute__((ext_vector_type(8))) short short8;
typedef __attribute__((ext_vector_type(4))) float floatx4;

__device__ __forceinline__ float lrelu(float t) { return fmaxf(t, SLOPE * t); }

__device__ __forceinline__ unsigned short f2bf(float f) {
    union { float f; unsigned int u; } x; x.f = f;
    unsigned int r = (x.u + 0x7fff + ((x.u >> 16) & 1)) >> 16;   // RNE
    return (unsigned short)r;
}
__device__ __forceinline__ float bf2f(unsigned short h) {
    union { unsigned int u; float f; } x; x.u = ((unsigned int)h) << 16;
    return x.f;
}

// BN affine for channel c from raw sums. st: [sum(256) | sumsq(256)].
__device__ __forceinline__ void bn_coeff(const float* __restrict__ st,
                                         const float* __restrict__ g,
                                         const float* __restrict__ be,
                                         float invN, int c, float& sc, float& sh) {
    float m   = st[c] * invN;
    float var = fmaf(st[256 + c], invN, -m * m);
    float r   = rsqrtf(var + BN_EPS);
    sc = g[c] * r;
    sh = fmaf(-sc, m, be[c]);
}

// ---------------------------------------------------------------------------
// Weight reorder: w[co][ci][t] fp32 -> Wr[t][co][ci_pad] bf16 (zero pad).
// ---------------------------------------------------------------------------
__global__ __launch_bounds__(256) void prepw_kernel(
    const float* __restrict__ w, unsigned short* __restrict__ wr,
    int Cout, int Cinpad, int Cin)
{
    int id = blockIdx.x * 256 + threadIdx.x;
    if (id >= 3 * Cout * Cinpad) return;
    int ci = id % Cinpad;
    int rest = id / Cinpad;
    int co = rest % Cout;
    int t  = rest / Cout;
    float v = (ci < Cin) ? w[((size_t)co * Cin + ci) * 3 + t] : 0.0f;
    wr[id] = f2bf(v);
}

// ---------------------------------------------------------------------------
// enc0: (B,1,16384) -> raw bf16 f0 [b][8192][64] + stats. Thread co = tid&63.
// Grid (64,1,8): each thread covers 32 output positions.
// ---------------------------------------------------------------------------
__global__ __launch_bounds__(256) void enc0_kernel(
    const float* __restrict__ x, const float* __restrict__ w,
    const float* __restrict__ bias, unsigned short* __restrict__ f0,
    float* __restrict__ st)
{
    __shared__ float ssum[64], ssq[64];
    const int tid = threadIdx.x;
    const int co  = tid & 63;
    const int b   = blockIdx.z;
    if (tid < 64) { ssum[tid] = 0.f; ssq[tid] = 0.f; }
    __syncthreads();
    const float w0 = w[co * 3], w1 = w[co * 3 + 1], w2 = w[co * 3 + 2];
    const float bs = bias[co];
    const float* xb = x + (size_t)b * 16384;
    float lsum = 0.f, lsq = 0.f;
    const int obase = blockIdx.x * 128 + (tid >> 6) * 32;
    for (int k = 0; k < 32; ++k) {
        int o = obase + k;
        int xi = 2 * o - 1;
        float x0v = (xi >= 0) ? xb[xi] : 0.f;
        float a = bs;
        a = fmaf(w0, x0v, a);
        a = fmaf(w1, xb[xi + 1], a);
        a = fmaf(w2, xb[xi + 2], a);
        f0[((size_t)(b * 8192 + o)) * 64 + co] = f2bf(a);
        lsum += a; lsq = fmaf(a, a, lsq);
    }
    atomicAdd(&ssum[co], lsum);
    atomicAdd(&ssq[co], lsq);
    __syncthreads();
    if (tid < 64) {
        atomicAdd(&st[tid],       ssum[tid]);
        atomicAdd(&st[256 + tid], ssq[tid]);
    }
}

// ---------------------------------------------------------------------------
// MFMA implicit-GEMM conv. Channel-last bf16 in/out.
// D[pos][co] = sum_{t,ci} X[pos*STRIDE-1+t][ci] * Wr[t][co][ci]
// WG = 4 waves; tile M=256 pos x N=64 co; per wave M=64 (4 pos-subtiles),
// 4 co-subtiles, acc = 16 x float4. K-chunks of 32 channels x 3 taps.
// Source B (chunks >= CAc) read through x2 nearest upsample (pos>>1).
// Writes raw bf16 out + per-channel (sum,sumsq) atomics.
// ---------------------------------------------------------------------------
template<int STRIDE>
__global__ __launch_bounds__(256) void conv_mfma_kernel(
    const unsigned short* __restrict__ xA, int CAc,
    const unsigned short* __restrict__ xB, int CBc,
    const unsigned short* __restrict__ Wr, const float* __restrict__ bias,
    unsigned short* __restrict__ out, int L_in, int L_out, int Cout,
    float* __restrict__ st)
{
    constexpr int SEG = 255 * STRIDE + 3;
    __shared__ __align__(16) unsigned short x_tile[SEG * 32];
    __shared__ __align__(16) unsigned short w_tile[3 * 64 * 32];
    __shared__ float ssum[64], ssq[64];

    const int tid  = threadIdx.x;
    const int wv   = tid >> 6;
    const int lane = tid & 63;
    const int col  = lane & 15;
    const int quad = lane >> 4;
    const int oblk = blockIdx.x * 256;
    const int cob  = blockIdx.y * 64;
    const int b    = blockIdx.z;
    const int nch    = CAc + CBc;
    const int CApad  = CAc * 32;
    const int CBpad  = CBc * 32;
    const int Cinpad = nch * 32;
    const int LB     = L_in >> 1;

    if (tid < 64) { ssum[tid] = 0.f; ssq[tid] = 0.f; }

    floatx4 acc[4][4];
    #pragma unroll
    for (int ps = 0; ps < 4; ++ps)
        #pragma unroll
        for (int s = 0; s < 4; ++s)
            acc[ps][s] = (floatx4){0.f, 0.f, 0.f, 0.f};

    const int x0 = oblk * STRIDE - 1;

    for (int ch = 0; ch < nch; ++ch) {
        __syncthreads();
        // ---- stage x tile: SEG rows x 32 ch, 16B pieces ----
        for (int r = tid; r < SEG * 4; r += 256) {
            const int pi = r >> 2, part = r & 3;
            const int gp = x0 + pi;
            short8 v = {0, 0, 0, 0, 0, 0, 0, 0};
            if (gp >= 0 && gp < L_in) {
                if (ch < CAc)
                    v = *(const short8*)(xA + ((size_t)b * L_in + gp) * CApad + ch * 32 + part * 8);
                else
                    v = *(const short8*)(xB + ((size_t)b * LB + (gp >> 1)) * CBpad + (ch - CAc) * 32 + part * 8);
            }
            *(short8*)(x_tile + pi * 32 + part * 8) = v;
        }
        // ---- stage weight tile: [3][64 co][32 ci] = 768 16B pieces ----
        for (int r = tid; r < 768; r += 256) {
            const int part = r & 3;
            const int co   = (r >> 2) & 63;
            const int t    = r >> 8;
            short8 v = *(const short8*)(Wr + ((size_t)t * Cout + cob + co) * Cinpad + ch * 32 + part * 8);
            *(short8*)(w_tile + (t * 64 + co) * 32 + part * 8) = v;
        }
        __syncthreads();
        // ---- MFMA: 3 taps x 4 pos-subtiles x 4 co-subtiles ----
        #pragma unroll
        for (int t = 0; t < 3; ++t) {
            short8 bfr[4];
            #pragma unroll
            for (int s = 0; s < 4; ++s)
                bfr[s] = *(const short8*)(w_tile + (t * 64 + s * 16 + col) * 32 + quad * 8);
            #pragma unroll
            for (int ps = 0; ps < 4; ++ps) {
                const int xi = (wv * 64 + ps * 16 + col) * STRIDE + t;
                short8 afr = *(const short8*)(x_tile + xi * 32 + quad * 8);
                #pragma unroll
                for (int s = 0; s < 4; ++s)
                    acc[ps][s] = __builtin_amdgcn_mfma_f32_16x16x32_bf16(afr, bfr[s], acc[ps][s], 0, 0, 0);
            }
        }
    }

    // ---- bias ----
    float bv[4];
    #pragma unroll
    for (int s = 0; s < 4; ++s) bv[s] = bias[cob + s * 16 + col];
    #pragma unroll
    for (int ps = 0; ps < 4; ++ps)
        #pragma unroll
        for (int s = 0; s < 4; ++s)
            #pragma unroll
            for (int r = 0; r < 4; ++r)
                acc[ps][s][r] += bv[s];

    // ---- store raw bf16 (D: row = quad*4+reg -> pos, col -> co) ----
    #pragma unroll
    for (int ps = 0; ps < 4; ++ps) {
        const int pos0 = oblk + wv * 64 + ps * 16 + quad * 4;
        #pragma unroll
        for (int s = 0; s < 4; ++s) {
            unsigned short* op = out + ((size_t)b * L_out + pos0) * Cout + cob + s * 16 + col;
            #pragma unroll
            for (int r = 0; r < 4; ++r)
                op[(size_t)r * Cout] = f2bf(acc[ps][s][r]);
        }
    }

    // ---- stats: per-co sum/sumsq ----
    #pragma unroll
    for (int s = 0; s < 4; ++s) {
        float v = 0.f, q = 0.f;
        #pragma unroll
        for (int ps = 0; ps < 4; ++ps)
            #pragma unroll
            for (int r = 0; r < 4; ++r) {
                float a = acc[ps][s][r];
                v += a; q = fmaf(a, a, q);
            }
        v += __shfl_xor(v, 16); v += __shfl_xor(v, 32);
        q += __shfl_xor(q, 16); q += __shfl_xor(q, 32);
        if (quad == 0) {
            atomicAdd(&ssum[s * 16 + col], v);
            atomicAdd(&ssq[s * 16 + col],  q);
        }
    }
    __syncthreads();
    if (tid < 64) {
        atomicAdd(&st[cob + tid],       ssum[tid]);
        atomicAdd(&st[256 + cob + tid], ssq[tid]);
    }
}

// ---------------------------------------------------------------------------
// In-place BN + LeakyReLU on bf16 channel-last buffer. Coeffs cached in LDS.
// ---------------------------------------------------------------------------
__global__ __launch_bounds__(256) void bn_kernel(
    unsigned short* __restrict__ y, const float* __restrict__ st,
    const float* __restrict__ g, const float* __restrict__ be,
    float invN, int C, int n8)
{
    __shared__ float lsc[256], lsh[256];
    const int tid = threadIdx.x;
    if (tid < C) {
        float sc, sh;
        bn_coeff(st, g, be, invN, tid, sc, sh);
        lsc[tid] = sc; lsh[tid] = sh;
    }
    __syncthreads();
    int idx = blockIdx.x * 256 + tid;
    if (idx < n8) {
        short8 v = *(short8*)(y + (size_t)idx * 8);
        int c0 = (idx * 8) & (C - 1);
        #pragma unroll
        for (int j = 0; j < 8; ++j) {
            float f = bf2f((unsigned short)v[j]);
            f = lrelu(fmaf(f, lsc[c0 + j], lsh[c0 + j]));
            v[j] = (short)f2bf(f);
        }
        *(short8*)(y + (size_t)idx * 8) = v;
    }
}

// ---------------------------------------------------------------------------
// Banded correlation fusion on normalized f2 (bf16 [b][2048][256]).
// Block per (i, b); thread c = tid; 11 displacements reduced per block.
// Output featn bf16 [b][2048][32] (11 used, 21 zeros).
// ---------------------------------------------------------------------------
__global__ __launch_bounds__(256) void fusion_kernel(
    const unsigned short* __restrict__ f2, unsigned short* __restrict__ feat)
{
    __shared__ float fs[11];
    const int tid = threadIdx.x;
    const int i = blockIdx.x;
    const int b = blockIdx.y;
    if (tid < 11) fs[tid] = 0.f;
    __syncthreads();
    const unsigned short* base = f2 + (size_t)b * 2048 * 256;
    const int c = tid;
    float a0 = bf2f(base[(size_t)max(i - 1, 0) * 256 + c]);
    float a1 = bf2f(base[(size_t)i * 256 + c]);
    float a2 = bf2f(base[(size_t)min(i + 1, 2047) * 256 + c]);
    #pragma unroll
    for (int d = -5; d <= 5; ++d) {
        int i2 = min(max(i + d, 0), 2047);
        float s = 0.f;
        s = fmaf(a0, bf2f(base[(size_t)max(i2 - 1, 0) * 256 + c]), s);
        s = fmaf(a1, bf2f(base[(size_t)i2 * 256 + c]), s);
        s = fmaf(a2, bf2f(base[(size_t)min(i2 + 1, 2047) * 256 + c]), s);
        #pragma unroll
        for (int off = 1; off < 64; off <<= 1) s += __shfl_xor(s, off);
        if ((tid & 63) == 0) atomicAdd(&fs[d + 5], s);
    }
    __syncthreads();
    if (tid < 32) {
        float v = (tid < 11) ? fs[tid] : 0.f;
        feat[((size_t)(b * 2048 + i)) * 32 + tid] = f2bf(v);
    }
}

// ---------------------------------------------------------------------------
// Flow head conv (K=1, Cout=2): concat(scan1, up2(d0n bf16)) -> raw fp32
// [b][16384][2] + stats.
// ---------------------------------------------------------------------------
__global__ __launch_bounds__(256) void flow_kernel(
    const float* __restrict__ scan1, const unsigned short* __restrict__ d0,
    const float* __restrict__ fw, const float* __restrict__ fb,
    float* __restrict__ outr, float* __restrict__ st)
{
    __shared__ float s4[4][4];
    const int tid = threadIdx.x;
    const int b = blockIdx.z;
    const int i = blockIdx.x * 256 + tid;
    float sv = scan1[(size_t)b * 16384 + i];
    const unsigned short* row = d0 + ((size_t)(b * 8192 + (i >> 1))) * 128;
    float a0 = fmaf(fw[0],   sv, fb[0]);
    float a1 = fmaf(fw[129], sv, fb[1]);
    for (int c8 = 0; c8 < 16; ++c8) {
        short8 v = *(const short8*)(row + c8 * 8);
        #pragma unroll
        for (int j = 0; j < 8; ++j) {
            float f = bf2f((unsigned short)v[j]);
            int cc = c8 * 8 + j;
            a0 = fmaf(fw[1 + cc],   f, a0);
            a1 = fmaf(fw[130 + cc], f, a1);
        }
    }
    float2 o; o.x = a0; o.y = a1;
    *(float2*)(outr + ((size_t)(b * 16384 + i)) * 2) = o;
    float s0 = a0, q0 = a0 * a0, s1 = a1, q1 = a1 * a1;
    #pragma unroll
    for (int off = 1; off < 64; off <<= 1) {
        s0 += __shfl_xor(s0, off); q0 += __shfl_xor(q0, off);
        s1 += __shfl_xor(s1, off); q1 += __shfl_xor(q1, off);
    }
    if ((tid & 63) == 0) {
        int w = tid >> 6;
        s4[w][0] = s0; s4[w][1] = q0; s4[w][2] = s1; s4[w][3] = q1;
    }
    __syncthreads();
    if (tid == 0) {
        float t0 = 0, t1 = 0, t2 = 0, t3 = 0;
        for (int w = 0; w < 4; ++w) {
            t0 += s4[w][0]; t1 += s4[w][1]; t2 += s4[w][2]; t3 += s4[w][3];
        }
        atomicAdd(&st[0],   t0); atomicAdd(&st[256],     t1);
        atomicAdd(&st[1],   t2); atomicAdd(&st[256 + 1], t3);
    }
}

// Final: BN + lrelu on flow raw -> d_out (B,N,2) fp32 (same layout).
__global__ __launch_bounds__(256) void final_kernel(
    const float* __restrict__ raw, const float* __restrict__ st,
    const float* __restrict__ g, const float* __restrict__ be,
    float invN, float* __restrict__ out)
{
    int idx = blockIdx.x * 256 + threadIdx.x;
    float sc0, sh0, sc1, sh1;
    bn_coeff(st, g, be, invN, 0, sc0, sh0);
    bn_coeff(st, g, be, invN, 1, sc1, sh1);
    float2 v = *(const float2*)(raw + (size_t)idx * 2);
    float2 o;
    o.x = lrelu(fmaf(v.x, sc0, sh0));
    o.y = lrelu(fmaf(v.y, sc1, sh1));
    *(float2*)(out + (size_t)idx * 2) = o;
}

// ---------------------------------------------------------------------------

extern "C" void kernel_launch(void* const* d_in, const int* in_sizes, int n_in,
                              void* d_out, int out_size, void* d_ws, size_t ws_size,
                              hipStream_t stream)
{
    const int B = 8;
    const float* scan1 = (const float*)d_in[0];
    const float* enc0_w = (const float*)d_in[1];
    const float* enc0_b = (const float*)d_in[2];
    const float* enc0_g = (const float*)d_in[3];
    const float* enc0_be= (const float*)d_in[4];
    const float* enc1_w = (const float*)d_in[5];
    const float* enc1_b = (const float*)d_in[6];
    const float* enc1_g = (const float*)d_in[7];
    const float* enc1_be= (const float*)d_in[8];
    const float* enc2_w = (const float*)d_in[9];
    const float* enc2_b = (const float*)d_in[10];
    const float* enc2_g = (const float*)d_in[11];
    const float* enc2_be= (const float*)d_in[12];
    const float* dec1_w = (const float*)d_in[13];
    const float* dec1_b = (const float*)d_in[14];
    const float* dec1_g = (const float*)d_in[15];
    const float* dec1_be= (const float*)d_in[16];
    const float* dec0_w = (const float*)d_in[17];
    const float* dec0_b = (const float*)d_in[18];
    const float* dec0_g = (const float*)d_in[19];
    const float* dec0_be= (const float*)d_in[20];
    const float* flow_w = (const float*)d_in[21];
    const float* flow_b = (const float*)d_in[22];
    const float* flow_g = (const float*)d_in[23];
    const float* flow_be= (const float*)d_in[24];

    char* ws = (char*)d_ws;
    unsigned short* f0    = (unsigned short*)(ws);             // 8 MiB  [8][8192][64]
    unsigned short* f1    = (unsigned short*)(ws + 8388608);   // 8 MiB  [8][4096][128]
    unsigned short* f2    = (unsigned short*)(ws + 16777216);  // 8 MiB  [8][2048][256]
    unsigned short* featn = (unsigned short*)(ws + 25165824);  // 1 MiB  [8][2048][32]
    unsigned short* d1    = (unsigned short*)(ws + 26214400);  // 8 MiB  [8][4096][128]
    unsigned short* d0    = (unsigned short*)(ws + 34603008);  // 16 MiB [8][8192][128]
    float*  flow_r = (float*)(ws + 51380224);                  // 1 MiB  [8][16384][2]
    unsigned short* wr1 = (unsigned short*)(ws + 52428800);    // 48 KiB  [3][128][64]
    unsigned short* wr2 = (unsigned short*)(ws + 52477952);    // 192 KiB [3][256][128]
    unsigned short* wr3 = (unsigned short*)(ws + 52674560);    // 120 KiB [3][128][160]
    unsigned short* wr4 = (unsigned short*)(ws + 52797440);    // 144 KiB [3][128][192]
    float* st = (float*)(ws + 52944896);                       // 6 x 512 floats
    float* st0 = st, *st1 = st + 512, *st2 = st + 1024;
    float* st3 = st + 1536, *st4 = st + 2048, *st5 = st + 2560;

    const float iN0 = 1.0f / (B * 8192.0f);
    const float iN1 = 1.0f / (B * 4096.0f);
    const float iN2 = 1.0f / (B * 2048.0f);
    const float iN3 = 1.0f / (B * 4096.0f);
    const float iN4 = 1.0f / (B * 8192.0f);
    const float iN5 = 1.0f / (B * 16384.0f);

    hipMemsetAsync(st, 0, 6 * 512 * sizeof(float), stream);

    prepw_kernel<<<(3 * 128 * 64  + 255) / 256, 256, 0, stream>>>(enc1_w, wr1, 128, 64, 64);
    prepw_kernel<<<(3 * 256 * 128 + 255) / 256, 256, 0, stream>>>(enc2_w, wr2, 256, 128, 128);
    prepw_kernel<<<(3 * 128 * 160 + 255) / 256, 256, 0, stream>>>(dec1_w, wr3, 128, 160, 139);
    prepw_kernel<<<(3 * 128 * 192 + 255) / 256, 256, 0, stream>>>(dec0_w, wr4, 128, 192, 192);

    // enc0 (VALU) + BN
    enc0_kernel<<<dim3(64, 1, B), 256, 0, stream>>>(scan1, enc0_w, enc0_b, f0, st0);
    bn_kernel<<<2048, 256, 0, stream>>>(f0, st0, enc0_g, enc0_be, iN0, 64, 524288);

    // enc1 (MFMA, stride 2): f0n -> f1 raw
    conv_mfma_kernel<2><<<dim3(16, 2, B), 256, 0, stream>>>(
        f0, 2, nullptr, 0, wr1, enc1_b, f1, 8192, 4096, 128, st1);
    bn_kernel<<<2048, 256, 0, stream>>>(f1, st1, enc1_g, enc1_be, iN1, 128, 524288);

    // enc2 (MFMA, stride 2): f1n -> f2 raw
    conv_mfma_kernel<2><<<dim3(8, 4, B), 256, 0, stream>>>(
        f1, 4, nullptr, 0, wr2, enc2_b, f2, 4096, 2048, 256, st2);
    bn_kernel<<<2048, 256, 0, stream>>>(f2, st2, enc2_g, enc2_be, iN2, 256, 524288);

    // fusion on f2n
    fusion_kernel<<<dim3(2048, B), 256, 0, stream>>>(f2, featn);

    // dec1 (MFMA, stride 1): concat(f1n, up2(featn)) -> d1 raw
    conv_mfma_kernel<1><<<dim3(16, 2, B), 256, 0, stream>>>(
        f1, 4, featn, 1, wr3, dec1_b, d1, 4096, 4096, 128, st3);
    bn_kernel<<<2048, 256, 0, stream>>>(d1, st3, dec1_g, dec1_be, iN3, 128, 524288);

    // dec0 (MFMA, stride 1): concat(f0n, up2(d1n)) -> d0 raw
    conv_mfma_kernel<1><<<dim3(32, 2, B), 256, 0, stream>>>(
        f0, 2, d1, 4, wr4, dec0_b, d0, 8192, 8192, 128, st4);
    bn_kernel<<<4096, 256, 0, stream>>>(d0, st4, dec0_g, dec0_be, iN4, 128, 1048576);

    // flow head (VALU) + final BN/transpose
    flow_kernel<<<dim3(64, 1, B), 256, 0, stream>>>(scan1, d0, flow_w, flow_b, flow_r, st5);
    final_kernel<<<512, 256, 0, stream>>>(flow_r, st5, flow_g, flow_be, iN5, (float*)d_out);
}

// Round 8
// 280.405 us; speedup vs baseline: 14.7570x; 1.1629x over previous
//
#include <hip/hip_runtime.h>
#include <cstddef>

#define SLOPE 0.01f
#define BN_EPS 1e-5f

typedef __attribute__((ext_vector_type(8))) short short8;
typedef __attribute__((ext_vector_type(4))) float floatx4;

__device__ __forceinline__ float lrelu(float t) { return fmaxf(t, SLOPE * t); }

__device__ __forceinline__ unsigned short f2bf(float f) {
    union { float f; unsigned int u; } x; x.f = f;
    unsigned int r = (x.u + 0x7fff + ((x.u >> 16) & 1)) >> 16;   // RNE
    return (unsigned short)r;
}
__device__ __forceinline__ float bf2f(unsigned short h) {
    union { unsigned int u; float f; } x; x.u = ((unsigned int)h) << 16;
    return x.f;
}

// BN affine for channel c from raw sums. st: [sum(256) | sumsq(256)].
__device__ __forceinline__ void bn_coeff(const float* __restrict__ st,
                                         const float* __restrict__ g,
                                         const float* __restrict__ be,
                                         float invN, int c, float& sc, float& sh) {
    float m   = st[c] * invN;
    float var = fmaf(st[256 + c], invN, -m * m);
    float r   = rsqrtf(var + BN_EPS);
    sc = g[c] * r;
    sh = fmaf(-sc, m, be[c]);
}

// ---------------------------------------------------------------------------
// Weight reorder: w[co][ci][t] fp32 -> Wr[t][co][ci_pad] bf16 (zero pad).
// ---------------------------------------------------------------------------
__global__ __launch_bounds__(256) void prepw_kernel(
    const float* __restrict__ w, unsigned short* __restrict__ wr,
    int Cout, int Cinpad, int Cin)
{
    int id = blockIdx.x * 256 + threadIdx.x;
    if (id >= 3 * Cout * Cinpad) return;
    int ci = id % Cinpad;
    int rest = id / Cinpad;
    int co = rest % Cout;
    int t  = rest / Cout;
    float v = (ci < Cin) ? w[((size_t)co * Cin + ci) * 3 + t] : 0.0f;
    wr[id] = f2bf(v);
}

// ---------------------------------------------------------------------------
// enc0: (B,1,16384) -> raw bf16 f0 [b][8192][64] + stats. Thread co = tid&63.
// ---------------------------------------------------------------------------
__global__ __launch_bounds__(256) void enc0_kernel(
    const float* __restrict__ x, const float* __restrict__ w,
    const float* __restrict__ bias, unsigned short* __restrict__ f0,
    float* __restrict__ st)
{
    __shared__ float ssum[64], ssq[64];
    const int tid = threadIdx.x;
    const int co  = tid & 63;
    const int b   = blockIdx.z;
    if (tid < 64) { ssum[tid] = 0.f; ssq[tid] = 0.f; }
    __syncthreads();
    const float w0 = w[co * 3], w1 = w[co * 3 + 1], w2 = w[co * 3 + 2];
    const float bs = bias[co];
    const float* xb = x + (size_t)b * 16384;
    float lsum = 0.f, lsq = 0.f;
    const int obase = blockIdx.x * 128 + (tid >> 6) * 32;
    for (int k = 0; k < 32; ++k) {
        int o = obase + k;
        int xi = 2 * o - 1;
        float x0v = (xi >= 0) ? xb[xi] : 0.f;
        float a = bs;
        a = fmaf(w0, x0v, a);
        a = fmaf(w1, xb[xi + 1], a);
        a = fmaf(w2, xb[xi + 2], a);
        f0[((size_t)(b * 8192 + o)) * 64 + co] = f2bf(a);
        lsum += a; lsq = fmaf(a, a, lsq);
    }
    atomicAdd(&ssum[co], lsum);
    atomicAdd(&ssq[co], lsq);
    __syncthreads();
    if (tid < 64) {
        atomicAdd(&st[tid],       ssum[tid]);
        atomicAdd(&st[256 + tid], ssq[tid]);
    }
}

// ---------------------------------------------------------------------------
// MFMA implicit-GEMM conv (channel-last bf16). See R7 notes.
// ---------------------------------------------------------------------------
template<int STRIDE>
__global__ __launch_bounds__(256) void conv_mfma_kernel(
    const unsigned short* __restrict__ xA, int CAc,
    const unsigned short* __restrict__ xB, int CBc,
    const unsigned short* __restrict__ Wr, const float* __restrict__ bias,
    unsigned short* __restrict__ out, int L_in, int L_out, int Cout,
    float* __restrict__ st)
{
    constexpr int SEG = 255 * STRIDE + 3;
    __shared__ __align__(16) unsigned short x_tile[SEG * 32];
    __shared__ __align__(16) unsigned short w_tile[3 * 64 * 32];
    __shared__ float ssum[64], ssq[64];

    const int tid  = threadIdx.x;
    const int wv   = tid >> 6;
    const int lane = tid & 63;
    const int col  = lane & 15;
    const int quad = lane >> 4;
    const int oblk = blockIdx.x * 256;
    const int cob  = blockIdx.y * 64;
    const int b    = blockIdx.z;
    const int nch    = CAc + CBc;
    const int CApad  = CAc * 32;
    const int CBpad  = CBc * 32;
    const int Cinpad = nch * 32;
    const int LB     = L_in >> 1;

    if (tid < 64) { ssum[tid] = 0.f; ssq[tid] = 0.f; }

    floatx4 acc[4][4];
    #pragma unroll
    for (int ps = 0; ps < 4; ++ps)
        #pragma unroll
        for (int s = 0; s < 4; ++s)
            acc[ps][s] = (floatx4){0.f, 0.f, 0.f, 0.f};

    const int x0 = oblk * STRIDE - 1;

    for (int ch = 0; ch < nch; ++ch) {
        __syncthreads();
        for (int r = tid; r < SEG * 4; r += 256) {
            const int pi = r >> 2, part = r & 3;
            const int gp = x0 + pi;
            short8 v = {0, 0, 0, 0, 0, 0, 0, 0};
            if (gp >= 0 && gp < L_in) {
                if (ch < CAc)
                    v = *(const short8*)(xA + ((size_t)b * L_in + gp) * CApad + ch * 32 + part * 8);
                else
                    v = *(const short8*)(xB + ((size_t)b * LB + (gp >> 1)) * CBpad + (ch - CAc) * 32 + part * 8);
            }
            *(short8*)(x_tile + pi * 32 + part * 8) = v;
        }
        for (int r = tid; r < 768; r += 256) {
            const int part = r & 3;
            const int co   = (r >> 2) & 63;
            const int t    = r >> 8;
            short8 v = *(const short8*)(Wr + ((size_t)t * Cout + cob + co) * Cinpad + ch * 32 + part * 8);
            *(short8*)(w_tile + (t * 64 + co) * 32 + part * 8) = v;
        }
        __syncthreads();
        #pragma unroll
        for (int t = 0; t < 3; ++t) {
            short8 bfr[4];
            #pragma unroll
            for (int s = 0; s < 4; ++s)
                bfr[s] = *(const short8*)(w_tile + (t * 64 + s * 16 + col) * 32 + quad * 8);
            #pragma unroll
            for (int ps = 0; ps < 4; ++ps) {
                const int xi = (wv * 64 + ps * 16 + col) * STRIDE + t;
                short8 afr = *(const short8*)(x_tile + xi * 32 + quad * 8);
                #pragma unroll
                for (int s = 0; s < 4; ++s)
                    acc[ps][s] = __builtin_amdgcn_mfma_f32_16x16x32_bf16(afr, bfr[s], acc[ps][s], 0, 0, 0);
            }
        }
    }

    float bv[4];
    #pragma unroll
    for (int s = 0; s < 4; ++s) bv[s] = bias[cob + s * 16 + col];
    #pragma unroll
    for (int ps = 0; ps < 4; ++ps)
        #pragma unroll
        for (int s = 0; s < 4; ++s)
            #pragma unroll
            for (int r = 0; r < 4; ++r)
                acc[ps][s][r] += bv[s];

    #pragma unroll
    for (int ps = 0; ps < 4; ++ps) {
        const int pos0 = oblk + wv * 64 + ps * 16 + quad * 4;
        #pragma unroll
        for (int s = 0; s < 4; ++s) {
            unsigned short* op = out + ((size_t)b * L_out + pos0) * Cout + cob + s * 16 + col;
            #pragma unroll
            for (int r = 0; r < 4; ++r)
                op[(size_t)r * Cout] = f2bf(acc[ps][s][r]);
        }
    }

    #pragma unroll
    for (int s = 0; s < 4; ++s) {
        float v = 0.f, q = 0.f;
        #pragma unroll
        for (int ps = 0; ps < 4; ++ps)
            #pragma unroll
            for (int r = 0; r < 4; ++r) {
                float a = acc[ps][s][r];
                v += a; q = fmaf(a, a, q);
            }
        v += __shfl_xor(v, 16); v += __shfl_xor(v, 32);
        q += __shfl_xor(q, 16); q += __shfl_xor(q, 32);
        if (quad == 0) {
            atomicAdd(&ssum[s * 16 + col], v);
            atomicAdd(&ssq[s * 16 + col],  q);
        }
    }
    __syncthreads();
    if (tid < 64) {
        atomicAdd(&st[cob + tid],       ssum[tid]);
        atomicAdd(&st[256 + cob + tid], ssq[tid]);
    }
}

// ---------------------------------------------------------------------------
// In-place BN + LeakyReLU on bf16 channel-last buffer.
// ---------------------------------------------------------------------------
__global__ __launch_bounds__(256) void bn_kernel(
    unsigned short* __restrict__ y, const float* __restrict__ st,
    const float* __restrict__ g, const float* __restrict__ be,
    float invN, int C, int n8)
{
    __shared__ float lsc[256], lsh[256];
    const int tid = threadIdx.x;
    if (tid < C) {
        float sc, sh;
        bn_coeff(st, g, be, invN, tid, sc, sh);
        lsc[tid] = sc; lsh[tid] = sh;
    }
    __syncthreads();
    int idx = blockIdx.x * 256 + tid;
    if (idx < n8) {
        short8 v = *(short8*)(y + (size_t)idx * 8);
        int c0 = (idx * 8) & (C - 1);
        #pragma unroll
        for (int j = 0; j < 8; ++j) {
            float f = bf2f((unsigned short)v[j]);
            f = lrelu(fmaf(f, lsc[c0 + j], lsh[c0 + j]));
            v[j] = (short)f2bf(f);
        }
        *(short8*)(y + (size_t)idx * 8) = v;
    }
}

// ---------------------------------------------------------------------------
// Banded correlation fusion, LDS-staged stencil. Block = 64 positions x 1
// batch; stage 76-row halo (ch stride padded to 272); thread = (pos, 64-ch
// quarter) with 11 private accumulators; 4-way shfl_xor reduce.
// corr[d,i] = sum_j S[cl(i+j), cl(cl(i+d)+j)], j=-1..1 (S = row dot).
// Output featn bf16 [b][2048][32] (11 used, 21 zeros).
// ---------------------------------------------------------------------------
__global__ __launch_bounds__(256) void fusion_kernel(
    const unsigned short* __restrict__ f2, unsigned short* __restrict__ feat)
{
    constexpr int ROWS = 76;          // 64 + 2*6 halo
    constexpr int CPAD = 272;         // padded channel stride
    __shared__ __align__(16) unsigned short tile[ROWS * CPAD];  // 41344 B
    const int tid = threadIdx.x;
    const int p0  = blockIdx.x * 64;
    const int b   = blockIdx.y;
    const unsigned short* base = f2 + (size_t)b * 2048 * 256;

    for (int r = tid; r < ROWS * 32; r += 256) {
        int row = r >> 5, piece = r & 31;
        int grow = min(max(p0 - 6 + row, 0), 2047);
        short8 v = *(const short8*)(base + (size_t)grow * 256 + piece * 8);
        *(short8*)(tile + row * CPAD + piece * 8) = v;
    }
    __syncthreads();

    const int il = tid >> 2;          // local position 0..63
    const int q  = tid & 3;           // channel quarter
    const int i  = p0 + il;

    float acc[11];
    #pragma unroll
    for (int d = 0; d < 11; ++d) acc[d] = 0.f;

    int ra[3];
    #pragma unroll
    for (int j = 0; j < 3; ++j)
        ra[j] = (min(max(i + j - 1, 0), 2047) - p0 + 6) * CPAD;
    int rb[11][3];
    #pragma unroll
    for (int d = 0; d < 11; ++d) {
        int i2 = min(max(i + d - 5, 0), 2047);
        #pragma unroll
        for (int j = 0; j < 3; ++j)
            rb[d][j] = (min(max(i2 + j - 1, 0), 2047) - p0 + 6) * CPAD;
    }

    for (int ck = 0; ck < 8; ++ck) {
        const int coff = q * 64 + ck * 8;
        float fa[3][8];
        #pragma unroll
        for (int j = 0; j < 3; ++j) {
            short8 v = *(const short8*)(tile + ra[j] + coff);
            #pragma unroll
            for (int e = 0; e < 8; ++e) fa[j][e] = bf2f((unsigned short)v[e]);
        }
        #pragma unroll
        for (int d = 0; d < 11; ++d) {
            #pragma unroll
            for (int j = 0; j < 3; ++j) {
                short8 v = *(const short8*)(tile + rb[d][j] + coff);
                #pragma unroll
                for (int e = 0; e < 8; ++e)
                    acc[d] = fmaf(fa[j][e], bf2f((unsigned short)v[e]), acc[d]);
            }
        }
    }

    #pragma unroll
    for (int d = 0; d < 11; ++d) {
        acc[d] += __shfl_xor(acc[d], 1);
        acc[d] += __shfl_xor(acc[d], 2);
    }
    if (q == 0) {
        unsigned short* op = feat + ((size_t)(b * 2048 + i)) * 32;
        #pragma unroll
        for (int d = 0; d < 11; ++d) op[d] = f2bf(acc[d]);
        #pragma unroll
        for (int d = 11; d < 32; ++d) op[d] = 0;
    }
}

// ---------------------------------------------------------------------------
// Flow head conv (K=1, Cout=2) + stats.
// ---------------------------------------------------------------------------
__global__ __launch_bounds__(256) void flow_kernel(
    const float* __restrict__ scan1, const unsigned short* __restrict__ d0,
    const float* __restrict__ fw, const float* __restrict__ fb,
    float* __restrict__ outr, float* __restrict__ st)
{
    __shared__ float s4[4][4];
    const int tid = threadIdx.x;
    const int b = blockIdx.z;
    const int i = blockIdx.x * 256 + tid;
    float sv = scan1[(size_t)b * 16384 + i];
    const unsigned short* row = d0 + ((size_t)(b * 8192 + (i >> 1))) * 128;
    float a0 = fmaf(fw[0],   sv, fb[0]);
    float a1 = fmaf(fw[129], sv, fb[1]);
    for (int c8 = 0; c8 < 16; ++c8) {
        short8 v = *(const short8*)(row + c8 * 8);
        #pragma unroll
        for (int j = 0; j < 8; ++j) {
            float f = bf2f((unsigned short)v[j]);
            int cc = c8 * 8 + j;
            a0 = fmaf(fw[1 + cc],   f, a0);
            a1 = fmaf(fw[130 + cc], f, a1);
        }
    }
    float2 o; o.x = a0; o.y = a1;
    *(float2*)(outr + ((size_t)(b * 16384 + i)) * 2) = o;
    float s0 = a0, q0 = a0 * a0, s1 = a1, q1 = a1 * a1;
    #pragma unroll
    for (int off = 1; off < 64; off <<= 1) {
        s0 += __shfl_xor(s0, off); q0 += __shfl_xor(q0, off);
        s1 += __shfl_xor(s1, off); q1 += __shfl_xor(q1, off);
    }
    if ((tid & 63) == 0) {
        int w = tid >> 6;
        s4[w][0] = s0; s4[w][1] = q0; s4[w][2] = s1; s4[w][3] = q1;
    }
    __syncthreads();
    if (tid == 0) {
        float t0 = 0, t1 = 0, t2 = 0, t3 = 0;
        for (int w = 0; w < 4; ++w) {
            t0 += s4[w][0]; t1 += s4[w][1]; t2 += s4[w][2]; t3 += s4[w][3];
        }
        atomicAdd(&st[0],   t0); atomicAdd(&st[256],     t1);
        atomicAdd(&st[1],   t2); atomicAdd(&st[256 + 1], t3);
    }
}

// Final: BN + lrelu on flow raw -> d_out (B,N,2) fp32.
__global__ __launch_bounds__(256) void final_kernel(
    const float* __restrict__ raw, const float* __restrict__ st,
    const float* __restrict__ g, const float* __restrict__ be,
    float invN, float* __restrict__ out)
{
    int idx = blockIdx.x * 256 + threadIdx.x;
    float sc0, sh0, sc1, sh1;
    bn_coeff(st, g, be, invN, 0, sc0, sh0);
    bn_coeff(st, g, be, invN, 1, sc1, sh1);
    float2 v = *(const float2*)(raw + (size_t)idx * 2);
    float2 o;
    o.x = lrelu(fmaf(v.x, sc0, sh0));
    o.y = lrelu(fmaf(v.y, sc1, sh1));
    *(float2*)(out + (size_t)idx * 2) = o;
}

// ---------------------------------------------------------------------------

extern "C" void kernel_launch(void* const* d_in, const int* in_sizes, int n_in,
                              void* d_out, int out_size, void* d_ws, size_t ws_size,
                              hipStream_t stream)
{
    const int B = 8;
    const float* scan1 = (const float*)d_in[0];
    const float* enc0_w = (const float*)d_in[1];
    const float* enc0_b = (const float*)d_in[2];
    const float* enc0_g = (const float*)d_in[3];
    const float* enc0_be= (const float*)d_in[4];
    const float* enc1_w = (const float*)d_in[5];
    const float* enc1_b = (const float*)d_in[6];
    const float* enc1_g = (const float*)d_in[7];
    const float* enc1_be= (const float*)d_in[8];
    const float* enc2_w = (const float*)d_in[9];
    const float* enc2_b = (const float*)d_in[10];
    const float* enc2_g = (const float*)d_in[11];
    const float* enc2_be= (const float*)d_in[12];
    const float* dec1_w = (const float*)d_in[13];
    const float* dec1_b = (const float*)d_in[14];
    const float* dec1_g = (const float*)d_in[15];
    const float* dec1_be= (const float*)d_in[16];
    const float* dec0_w = (const float*)d_in[17];
    const float* dec0_b = (const float*)d_in[18];
    const float* dec0_g = (const float*)d_in[19];
    const float* dec0_be= (const float*)d_in[20];
    const float* flow_w = (const float*)d_in[21];
    const float* flow_b = (const float*)d_in[22];
    const float* flow_g = (const float*)d_in[23];
    const float* flow_be= (const float*)d_in[24];

    char* ws = (char*)d_ws;
    unsigned short* f0    = (unsigned short*)(ws);             // 8 MiB  [8][8192][64]
    unsigned short* f1    = (unsigned short*)(ws + 8388608);   // 8 MiB  [8][4096][128]
    unsigned short* f2    = (unsigned short*)(ws + 16777216);  // 8 MiB  [8][2048][256]
    unsigned short* featn = (unsigned short*)(ws + 25165824);  // 1 MiB  [8][2048][32]
    unsigned short* d1    = (unsigned short*)(ws + 26214400);  // 8 MiB  [8][4096][128]
    unsigned short* d0    = (unsigned short*)(ws + 34603008);  // 16 MiB [8][8192][128]
    float*  flow_r = (float*)(ws + 51380224);                  // 1 MiB  [8][16384][2]
    unsigned short* wr1 = (unsigned short*)(ws + 52428800);    // [3][128][64]
    unsigned short* wr2 = (unsigned short*)(ws + 52477952);    // [3][256][128]
    unsigned short* wr3 = (unsigned short*)(ws + 52674560);    // [3][128][160]
    unsigned short* wr4 = (unsigned short*)(ws + 52797440);    // [3][128][192]
    float* st = (float*)(ws + 52944896);                       // 6 x 512 floats
    float* st0 = st, *st1 = st + 512, *st2 = st + 1024;
    float* st3 = st + 1536, *st4 = st + 2048, *st5 = st + 2560;

    const float iN0 = 1.0f / (B * 8192.0f);
    const float iN1 = 1.0f / (B * 4096.0f);
    const float iN2 = 1.0f / (B * 2048.0f);
    const float iN3 = 1.0f / (B * 4096.0f);
    const float iN4 = 1.0f / (B * 8192.0f);
    const float iN5 = 1.0f / (B * 16384.0f);

    hipMemsetAsync(st, 0, 6 * 512 * sizeof(float), stream);

    prepw_kernel<<<(3 * 128 * 64  + 255) / 256, 256, 0, stream>>>(enc1_w, wr1, 128, 64, 64);
    prepw_kernel<<<(3 * 256 * 128 + 255) / 256, 256, 0, stream>>>(enc2_w, wr2, 256, 128, 128);
    prepw_kernel<<<(3 * 128 * 160 + 255) / 256, 256, 0, stream>>>(dec1_w, wr3, 128, 160, 139);
    prepw_kernel<<<(3 * 128 * 192 + 255) / 256, 256, 0, stream>>>(dec0_w, wr4, 128, 192, 192);

    // enc0 (VALU) + BN
    enc0_kernel<<<dim3(64, 1, B), 256, 0, stream>>>(scan1, enc0_w, enc0_b, f0, st0);
    bn_kernel<<<2048, 256, 0, stream>>>(f0, st0, enc0_g, enc0_be, iN0, 64, 524288);

    // enc1 (MFMA, stride 2): f0n -> f1 raw
    conv_mfma_kernel<2><<<dim3(16, 2, B), 256, 0, stream>>>(
        f0, 2, nullptr, 0, wr1, enc1_b, f1, 8192, 4096, 128, st1);
    bn_kernel<<<2048, 256, 0, stream>>>(f1, st1, enc1_g, enc1_be, iN1, 128, 524288);

    // enc2 (MFMA, stride 2): f1n -> f2 raw
    conv_mfma_kernel<2><<<dim3(8, 4, B), 256, 0, stream>>>(
        f1, 4, nullptr, 0, wr2, enc2_b, f2, 4096, 2048, 256, st2);
    bn_kernel<<<2048, 256, 0, stream>>>(f2, st2, enc2_g, enc2_be, iN2, 256, 524288);

    // fusion on f2n (LDS-staged stencil)
    fusion_kernel<<<dim3(32, B), 256, 0, stream>>>(f2, featn);

    // dec1 (MFMA, stride 1): concat(f1n, up2(featn)) -> d1 raw
    conv_mfma_kernel<1><<<dim3(16, 2, B), 256, 0, stream>>>(
        f1, 4, featn, 1, wr3, dec1_b, d1, 4096, 4096, 128, st3);
    bn_kernel<<<2048, 256, 0, stream>>>(d1, st3, dec1_g, dec1_be, iN3, 128, 524288);

    // dec0 (MFMA, stride 1): concat(f0n, up2(d1n)) -> d0 raw
    conv_mfma_kernel<1><<<dim3(32, 2, B), 256, 0, stream>>>(
        f0, 2, d1, 4, wr4, dec0_b, d0, 8192, 8192, 128, st4);
    bn_kernel<<<4096, 256, 0, stream>>>(d0, st4, dec0_g, dec0_be, iN4, 128, 1048576);

    // flow head (VALU) + final BN/transpose
    flow_kernel<<<dim3(64, 1, B), 256, 0, stream>>>(scan1, d0, flow_w, flow_b, flow_r, st5);
    final_kernel<<<512, 256, 0, stream>>>(flow_r, st5, flow_g, flow_be, iN5, (float*)d_out);
}